// Round 1
// baseline (910.382 us; speedup 1.0000x reference)
//
#include <hip/hip_runtime.h>
#include <stdint.h>

// ---------------------------------------------------------------------------
// HConstructor (slot-attention block) on gfx950.  Round 5:
//   - three big GEMMs (kvq, dots, dots2) ported to 256x256 / BK=64 / 8-wave
//     8-phase-style schedule: 4-slot half-tile ring, global_load_lds staging
//     with pre-swizzled global source, 2-bit XOR LDS swizzle (8 lanes/slot =
//     b128 floor), counted vmcnt(2) (never drained in steady state), raw
//     s_barrier + sched_barrier(0), setprio around MFMA clusters.
//   - K-accumulation order identical to the old gemm128 -> outputs
//     bit-identical (absmax canary must stay 0.001953125).
//
// Pipeline:
//   x  = LN(inputs)                    [16384,512]  (bf16)
//   e0 = LN(mu + exp(ls)*noise)        [2048,512]   (bf16 hi+lo)
//   {k,v} = relu(x@W{k,v}+b), q2 = x@Wq+bq   (one fused gemm256, N=1536)
//   q = relu(e0@Wq+bq)                              (gemm64)
//   dots = q@k^T * SCALE  -> fp32 scratch in dots2 region   (gemm256)
//   attn1: softmax(+eps,renorm), top-10, updates -> e1[:,512:1024]
//   h = relu(e1@W1+b1)   SPLIT bf16 (3-term);  e = h@W2+b2 SPLIT -> OUTPUT 0
//   k2 = relu(e@Wk+bk)
//   dots2 = q2@k2^T*SCALE -> OUTPUT 2 (gemm256); attn2 -> OUTPUT 1 (H)
// ---------------------------------------------------------------------------

#define NN 16384
#define NE 2048
#define TOPK 10

static const float SCALE_F = 0.04419417382415922f;  // 512^-0.5
#define EPS_F 1e-8f

using bf16x8  = __attribute__((ext_vector_type(8))) __bf16;
using floatx4 = __attribute__((ext_vector_type(4))) float;

__device__ __forceinline__ unsigned f_as_u(float f) {
  union { float f; unsigned u; } v; v.f = f; return v.u;
}
__device__ __forceinline__ float u_as_f(unsigned u) {
  union { unsigned u; float f; } v; v.u = u; return v.f;
}
__device__ __forceinline__ unsigned short f2bf(float f) {
  unsigned u = f_as_u(f);
  unsigned r = u + 0x7fffu + ((u >> 16) & 1u);
  return (unsigned short)(r >> 16);
}
__device__ __forceinline__ float bf2f(unsigned short h) {
  return u_as_f(((unsigned)h) << 16);
}

// async global->LDS, 16 B per lane; LDS dst is wave-uniform base + lane*16
__device__ __forceinline__ void glds16(const unsigned short* g, unsigned short* l) {
  __builtin_amdgcn_global_load_lds(
      (const __attribute__((address_space(1))) unsigned int*)g,
      (__attribute__((address_space(3))) unsigned int*)l, 16, 0, 0);
}

// monotone float->u32 key; pack (value, col) so u64 max = (max val, tie->smaller col)
__device__ __forceinline__ unsigned fkey(float f) {
  unsigned u = f_as_u(f);
  return (u & 0x80000000u) ? ~u : (u | 0x80000000u);
}
__device__ __forceinline__ float funkey(unsigned k) {
  unsigned u = (k & 0x80000000u) ? (k ^ 0x80000000u) : ~k;
  return u_as_f(u);
}
__device__ __forceinline__ unsigned long long packkc(float v, int col) {
  return ((unsigned long long)fkey(v) << 32) | (unsigned)(~(unsigned)col);
}
__device__ __forceinline__ int unpack_col(unsigned long long w) {
  return (int)(~(unsigned)(w & 0xFFFFFFFFull));
}
__device__ __forceinline__ float unpack_val(unsigned long long w) {
  return funkey((unsigned)(w >> 32));
}
__device__ __forceinline__ unsigned long long shfl_xor_u64(unsigned long long x, int m) {
  unsigned lo = (unsigned)x, hi = (unsigned)(x >> 32);
  lo = __shfl_xor(lo, m, 64);
  hi = __shfl_xor(hi, m, 64);
  return ((unsigned long long)hi << 32) | lo;
}

// ---------------- weight transposes ----------------
__global__ void transpose_cast_kernel(const float* __restrict__ src,
                                      unsigned short* __restrict__ dhi,
                                      unsigned short* __restrict__ dlo,
                                      int K, int N) {
  __shared__ float tile[32][33];
  int n0 = blockIdx.x * 32, k0 = blockIdx.y * 32;
  int tx = threadIdx.x, ty = threadIdx.y;  // 32 x 8
  for (int r = ty; r < 32; r += 8)
    tile[r][tx] = src[(size_t)(k0 + r) * N + n0 + tx];
  __syncthreads();
  for (int r = ty; r < 32; r += 8) {
    float v = tile[tx][r];
    size_t o = (size_t)(n0 + r) * K + k0 + tx;
    unsigned short h = f2bf(v);
    dhi[o] = h;
    if (dlo) dlo[o] = f2bf(v - bf2f(h));
  }
}

__global__ void transpose_cast3_kernel(const float* __restrict__ s0,
                                       const float* __restrict__ s1,
                                       const float* __restrict__ s2,
                                       unsigned short* __restrict__ dhi) {
  __shared__ float tile[32][33];
  const float* src = blockIdx.z == 0 ? s0 : (blockIdx.z == 1 ? s1 : s2);
  unsigned short* d = dhi + (size_t)blockIdx.z * 512 * 512;
  int n0 = blockIdx.x * 32, k0 = blockIdx.y * 32;
  int tx = threadIdx.x, ty = threadIdx.y;
  for (int r = ty; r < 32; r += 8)
    tile[r][tx] = src[(size_t)(k0 + r) * 512 + n0 + tx];
  __syncthreads();
  for (int r = ty; r < 32; r += 8)
    d[(size_t)(n0 + r) * 512 + k0 + tx] = f2bf(tile[tx][r]);
}

// ---------------- block reduce (256 threads = 4 waves) ----------------
__device__ __forceinline__ float block_sum_256(float v, float* sm4) {
#pragma unroll
  for (int off = 32; off; off >>= 1) v += __shfl_down(v, off, 64);
  __syncthreads();
  if ((threadIdx.x & 63) == 0) sm4[threadIdx.x >> 6] = v;
  __syncthreads();
  return (sm4[0] + sm4[1]) + (sm4[2] + sm4[3]);
}

// ---------------- layernorm kernels ----------------
__global__ __launch_bounds__(256) void ln_x_kernel(
    const float* __restrict__ in, const float* __restrict__ w,
    const float* __restrict__ b, unsigned short* __restrict__ out_hi) {
  __shared__ float sm4[4];
  int row = blockIdx.x, tid = threadIdx.x;
  const float* r = in + (size_t)row * 512;
  float x0 = r[tid], x1 = r[tid + 256];
  float mu = block_sum_256(x0 + x1, sm4) * (1.0f / 512.0f);
  float d0 = x0 - mu, d1 = x1 - mu;
  float var = block_sum_256(d0 * d0 + d1 * d1, sm4) * (1.0f / 512.0f);
  float rs = rsqrtf(var + 1e-5f);
  out_hi[(size_t)row * 512 + tid]       = f2bf(d0 * rs * w[tid] + b[tid]);
  out_hi[(size_t)row * 512 + tid + 256] = f2bf(d1 * rs * w[tid + 256] + b[tid + 256]);
}

__global__ __launch_bounds__(256) void ln_e_kernel(
    const float* __restrict__ noise, const float* __restrict__ mu_e,
    const float* __restrict__ ls_e, const float* __restrict__ w,
    const float* __restrict__ b, unsigned short* __restrict__ e1_hi,
    unsigned short* __restrict__ e1_lo) {
  __shared__ float sm4[4];
  int row = blockIdx.x, tid = threadIdx.x;
  const float* r = noise + (size_t)row * 512;
  float x0 = mu_e[tid] + expf(ls_e[tid]) * r[tid];
  float x1 = mu_e[tid + 256] + expf(ls_e[tid + 256]) * r[tid + 256];
  float mu = block_sum_256(x0 + x1, sm4) * (1.0f / 512.0f);
  float d0 = x0 - mu, d1 = x1 - mu;
  float var = block_sum_256(d0 * d0 + d1 * d1, sm4) * (1.0f / 512.0f);
  float rs = rsqrtf(var + 1e-5f);
  float y0 = d0 * rs * w[tid] + b[tid];
  float y1 = d1 * rs * w[tid + 256] + b[tid + 256];
  size_t o = (size_t)row * 1024;
  unsigned short h0 = f2bf(y0), h1 = f2bf(y1);
  e1_hi[o + tid] = h0;             e1_lo[o + tid] = f2bf(y0 - bf2f(h0));
  e1_hi[o + tid + 256] = h1;       e1_lo[o + tid + 256] = f2bf(y1 - bf2f(h1));
}

// ---------------------------------------------------------------------------
// gemm256 core: 256x256 tile, K=512 (8 K-tiles of 64), 512 threads = 8 waves
// (2 M-waves x 4 N-waves).  A [M,512], B [N,512] row-major bf16.
//
// LDS: A ring = 4 half-slots of 16KB (128 rows x 64 cols bf16), B same.
//   tile t: A0(t)->slot (2t)&3, A1(t)->(2t+1)&3  (same for B).
// Swizzle (both sides, rule #21): phys_byte = logical_byte ^ (((byte>>9)&3)<<5)
//   within each 16KB half.  Read frags then hit 8 lanes per 16B bank-slot
//   (the ds_read_b128 floor) instead of 16.
// Row interleave: wave (wfm,wfn); frag im (0..7) covers A rows
//   im*32 + wfm*16 + lrow  ->  im 0..3 live in half0, 4..7 in half1, so each
//   half is consumed by exactly 2 of a tile's 4 phases.
// Per tile, 4 phases (quadrants (im-lo/hi) x (in-lo/hi)); each phase:
//   12x ds_read_b128 -> stage 1 half-tile (2 glds16/thread) -> [vmcnt] ->
//   s_barrier -> setprio(1) -> 16 MFMA -> setprio(0).
// Stage schedule (verified for slot liveness + >=2-barrier WAR gaps + vmcnt
// coverage): ph0(t): B0(t+1); ph1: A1(t+1); ph2: B1(t+1); ph3: A0(t+2);
// vmcnt(2) once per tile at ph3 (drain vmcnt(0) only at tile 6's ph3).
// ---------------------------------------------------------------------------

#define NOVM ((void)0)
#define VM2 asm volatile("s_waitcnt vmcnt(2)" ::: "memory")
#define VM0 asm volatile("s_waitcnt vmcnt(0)" ::: "memory")
#define NOSTAGE ((void)0)

// per-thread 2x glds16: wave-uniform LDS dest, pre-(inverse-)swizzled source
#define STAGE(G_, rowbase_, kb_, slotptr_)                                     \
  { const unsigned short* g0_ =                                                \
        (G_) + ((rowbase_) + (size_t)sr0) * 512 + (kb_) + sc0;                 \
    const unsigned short* g1_ =                                                \
        (G_) + ((rowbase_) + (size_t)sr1) * 512 + (kb_) + sc1;                 \
    glds16(g0_, (unsigned short*)((char*)(slotptr_) + wave * 1024));           \
    glds16(g1_, (unsigned short*)((char*)(slotptr_) + 8192 + wave * 1024)); }

#define PHASE(IM0_, IN0_, ASL_, BSL_, STAGE_STMT_, VM_)                        \
  {                                                                            \
    const char* Ap_ = ldsA_c + (ASL_) * 16384;                                 \
    const char* Bp_ = ldsB_c + (BSL_) * 16384;                                 \
    bf16x8 af_[4][2], bg_[2][2];                                               \
    _Pragma("unroll") for (int i_ = 0; i_ < 4; ++i_) {                         \
      af_[i_][0] = *(const bf16x8*)(Ap_ + aoff0 + i_ * 4096);                  \
      af_[i_][1] = *(const bf16x8*)(Ap_ + aoff1 + i_ * 4096);                  \
    }                                                                          \
    _Pragma("unroll") for (int j_ = 0; j_ < 2; ++j_) {                         \
      bg_[j_][0] = *(const bf16x8*)(Bp_ + boff0 + j_ * 8192);                  \
      bg_[j_][1] = *(const bf16x8*)(Bp_ + boff1 + j_ * 8192);                  \
    }                                                                          \
    STAGE_STMT_;                                                               \
    VM_;                                                                       \
    __builtin_amdgcn_sched_barrier(0);                                         \
    __builtin_amdgcn_s_barrier();                                              \
    __builtin_amdgcn_sched_barrier(0);                                         \
    __builtin_amdgcn_s_setprio(1);                                             \
    _Pragma("unroll") for (int i_ = 0; i_ < 4; ++i_)                           \
      _Pragma("unroll") for (int j_ = 0; j_ < 2; ++j_) {                       \
        acc[(IM0_) + i_][(IN0_) + j_] =                                        \
            __builtin_amdgcn_mfma_f32_16x16x32_bf16(                           \
                af_[i_][0], bg_[j_][0], acc[(IM0_) + i_][(IN0_) + j_], 0, 0, 0);\
        acc[(IM0_) + i_][(IN0_) + j_] =                                        \
            __builtin_amdgcn_mfma_f32_16x16x32_bf16(                           \
                af_[i_][1], bg_[j_][1], acc[(IM0_) + i_][(IN0_) + j_], 0, 0, 0);\
      }                                                                        \
    __builtin_amdgcn_s_setprio(0);                                             \
  }

#define GEMM256_CORE(A_, B_)                                                   \
  __shared__ __align__(16) char lds_all[131072];                               \
  char* ldsA_s = lds_all;                                                      \
  char* ldsB_s = lds_all + 65536;                                              \
  const char* ldsA_c = lds_all;                                                \
  const char* ldsB_c = lds_all + 65536;                                        \
  int tid = threadIdx.x, wave = tid >> 6, lane = tid & 63;                     \
  int lrow = lane & 15, quad = lane >> 4;                                      \
  int wfm = wave >> 2, wfn = wave & 3;                                         \
  int smask = ((lrow >> 2) & 3) << 5;                                          \
  int aoff0 = (wfm * 16 + lrow) * 128 + ((quad * 16) ^ smask);                 \
  int aoff1 = aoff0 ^ 64;                                                      \
  int boff0 = (wfn * 16 + lrow) * 128 + ((quad * 16) ^ smask);                 \
  int boff1 = boff0 ^ 64;                                                      \
  int p0_ = tid * 16, l0_ = p0_ ^ (((p0_ >> 9) & 3) << 5);                     \
  int sr0 = l0_ >> 7, sc0 = (l0_ & 127) >> 1;                                  \
  int p1_ = 8192 + tid * 16, l1_ = p1_ ^ (((p1_ >> 9) & 3) << 5);              \
  int sr1 = l1_ >> 7, sc1 = (l1_ & 127) >> 1;                                  \
  floatx4 acc[8][4];                                                           \
  { floatx4 z4_ = {0.f, 0.f, 0.f, 0.f};                                        \
    _Pragma("unroll") for (int i_ = 0; i_ < 8; ++i_)                           \
      _Pragma("unroll") for (int j_ = 0; j_ < 4; ++j_) acc[i_][j_] = z4_; }    \
  /* prologue: A0(0),B0(0),A1(0),B1(0),A0(1); wait all but newest half */      \
  STAGE(A_, bm, 0, ldsA_s)                                                     \
  STAGE(B_, bn, 0, ldsB_s)                                                     \
  STAGE(A_, bm + 128, 0, ldsA_s + 16384)                                       \
  STAGE(B_, bn + 128, 0, ldsB_s + 16384)                                       \
  STAGE(A_, bm, 64, ldsA_s + 32768)                                            \
  VM2;                                                                         \
  __builtin_amdgcn_sched_barrier(0);                                           \
  __builtin_amdgcn_s_barrier();                                                \
  __builtin_amdgcn_sched_barrier(0);                                           \
  for (int t2 = 0; t2 < 8; t2 += 2) {                                          \
    int kn = (t2 + 1) * 64, kn2 = (t2 + 2) * 64, kn3 = (t2 + 3) * 64;          \
    /* even tile t2: own slots A{0,1}/B{0,1} */                                \
    PHASE(0, 0, 0, 0, STAGE(B_, bn, kn, ldsB_s + 32768), NOVM)                 \
    PHASE(0, 2, 0, 1, STAGE(A_, bm + 128, kn, ldsA_s + 49152), NOVM)           \
    PHASE(4, 0, 1, 0, STAGE(B_, bn + 128, kn, ldsB_s + 49152), NOVM)           \
    if (t2 < 6) {                                                              \
      PHASE(4, 2, 1, 1, STAGE(A_, bm, kn2, ldsA_s), VM2)                       \
      /* odd tile t2+1: own slots A{2,3}/B{2,3} */                             \
      PHASE(0, 0, 2, 2, STAGE(B_, bn, kn2, ldsB_s), NOVM)                      \
      PHASE(0, 2, 2, 3, STAGE(A_, bm + 128, kn2, ldsA_s + 16384), NOVM)        \
      PHASE(4, 0, 3, 2, STAGE(B_, bn + 128, kn2, ldsB_s + 16384), NOVM)        \
      PHASE(4, 2, 3, 3, STAGE(A_, bm, kn3, ldsA_s + 32768), VM2)               \
    } else {                                                                   \
      PHASE(4, 2, 1, 1, NOSTAGE, VM0)                                          \
      PHASE(0, 0, 2, 2, NOSTAGE, NOVM)                                         \
      PHASE(0, 2, 2, 3, NOSTAGE, NOVM)                                         \
      PHASE(4, 0, 3, 2, NOSTAGE, NOVM)                                         \
      PHASE(4, 2, 3, 3, NOSTAGE, NOVM)                                         \
    }                                                                          \
    (void)kn3;                                                                 \
  }

// dots / dots2: C = alpha * A@B^T (fp32 out)
__global__ __launch_bounds__(512, 2) void gemm256_dots_kernel(
    const unsigned short* __restrict__ A, const unsigned short* __restrict__ B,
    float alpha, float* __restrict__ C, int ldc, int ntiles) {
  int nwg = (int)gridDim.x;
  int bid = (int)blockIdx.x;
  int wg = (bid & 7) * (nwg >> 3) + (bid >> 3);  // XCD-aware, nwg % 8 == 0
  size_t bm = (size_t)(wg / ntiles) * 256;
  size_t bn = (size_t)(wg % ntiles) * 256;
  GEMM256_CORE(A, B)
#pragma unroll
  for (int im = 0; im < 8; ++im) {
    size_t row0 = bm + im * 32 + wfm * 16 + quad * 4;
#pragma unroll
    for (int in = 0; in < 4; ++in) {
      size_t col = bn + in * 64 + wfn * 16 + lrow;
#pragma unroll
      for (int r = 0; r < 4; ++r)
        C[(row0 + r) * (size_t)ldc + col] = acc[im][in][r] * alpha;
    }
  }
}

// fused k/v/q2: A = x [16384,512]; B = Wcat [1536,512] (slabs: Wk, Wv, Wq).
// 256-col tile never crosses a 512-slab boundary.
__global__ __launch_bounds__(512, 2) void gemm256_kvq_kernel(
    const unsigned short* __restrict__ A, const unsigned short* __restrict__ B,
    const float* __restrict__ bk, const float* __restrict__ bv,
    const float* __restrict__ bq,
    unsigned short* __restrict__ khi, unsigned short* __restrict__ vhi,
    unsigned short* __restrict__ q2hi, int ntiles) {
  int nwg = (int)gridDim.x;
  int bid = (int)blockIdx.x;
  int wg = (bid & 7) * (nwg >> 3) + (bid >> 3);
  size_t bm = (size_t)(wg / ntiles) * 256;
  size_t bn = (size_t)(wg % ntiles) * 256;
  GEMM256_CORE(A, B)
  int mat = (int)(bn >> 9);
  int colbase = (int)(bn & 511);
  const float* bias = mat == 0 ? bk : (mat == 1 ? bv : bq);
  unsigned short* dst = mat == 0 ? khi : (mat == 1 ? vhi : q2hi);
  bool relu = mat < 2;
#pragma unroll
  for (int im = 0; im < 8; ++im) {
    size_t row0 = bm + im * 32 + wfm * 16 + quad * 4;
#pragma unroll
    for (int in = 0; in < 4; ++in) {
      int col = colbase + in * 64 + wfn * 16 + lrow;
      float bvv = bias[col];
#pragma unroll
      for (int r = 0; r < 4; ++r) {
        float v = acc[im][in][r] + bvv;
        if (relu) v = fmaxf(v, 0.0f);
        dst[(row0 + r) * 512 + col] = f2bf(v);
      }
    }
  }
}

// ---------------- GEMM, 64x64 tile, optional 3-term hi/lo split ----------------
template <bool SPLIT, bool RELU, bool HAS_BIAS, bool WF32, bool WHI, bool WLO>
__global__ __launch_bounds__(256) void gemm64_kernel(
    const unsigned short* __restrict__ Ahi, const unsigned short* __restrict__ Alo, int lda,
    const unsigned short* __restrict__ Bhi, const unsigned short* __restrict__ Blo, int K,
    const float* __restrict__ bias, float alpha,
    float* __restrict__ Cf, int ldc,
    unsigned short* __restrict__ Chi, unsigned short* __restrict__ Clo, int ldcb) {
  __shared__ __align__(16) unsigned short AsH[64 * 32];
  __shared__ __align__(16) unsigned short BsH[64 * 32];
  __shared__ __align__(16) unsigned short AsL[64 * 32];
  __shared__ __align__(16) unsigned short BsL[64 * 32];
  int tid = threadIdx.x, wave = tid >> 6, lane = tid & 63;
  int lrow = lane & 15, quad = lane >> 4;
  size_t bm = (size_t)blockIdx.x * 64, bn = (size_t)blockIdx.y * 64;
  int row = tid >> 2, off = (tid & 3) << 3;
  size_t aoff = (bm + row) * (size_t)lda + off;
  size_t boff = (bn + row) * (size_t)K + off;

  floatx4 zero4 = {0.f, 0.f, 0.f, 0.f};
  floatx4 acc[4];
#pragma unroll
  for (int t = 0; t < 4; ++t) acc[t] = zero4;

  for (int k0 = 0; k0 < K; k0 += 32) {
    uint4 ah = *(const uint4*)(Ahi + aoff + k0);
    uint4 bh = *(const uint4*)(Bhi + boff + k0);
    uint4 al, bl;
    if (SPLIT) {
      al = *(const uint4*)(Alo + aoff + k0);
      bl = *(const uint4*)(Blo + boff + k0);
    }
    __syncthreads();
    *(uint4*)&AsH[tid * 8] = ah;
    *(uint4*)&BsH[tid * 8] = bh;
    if (SPLIT) {
      *(uint4*)&AsL[tid * 8] = al;
      *(uint4*)&BsL[tid * 8] = bl;
    }
    __syncthreads();
    int ai = (wave * 16 + lrow) * 32 + quad * 8;
    bf16x8 aH = *(const bf16x8*)&AsH[ai];
    bf16x8 aL;
    if (SPLIT) aL = *(const bf16x8*)&AsL[ai];
#pragma unroll
    for (int t = 0; t < 4; ++t) {
      int bi = (t * 16 + lrow) * 32 + quad * 8;
      bf16x8 bH = *(const bf16x8*)&BsH[bi];
      acc[t] = __builtin_amdgcn_mfma_f32_16x16x32_bf16(aH, bH, acc[t], 0, 0, 0);
      if (SPLIT) {
        bf16x8 bL = *(const bf16x8*)&BsL[bi];
        acc[t] = __builtin_amdgcn_mfma_f32_16x16x32_bf16(aH, bL, acc[t], 0, 0, 0);
        acc[t] = __builtin_amdgcn_mfma_f32_16x16x32_bf16(aL, bH, acc[t], 0, 0, 0);
      }
    }
  }
  size_t row0 = bm + wave * 16 + quad * 4;
#pragma unroll
  for (int t = 0; t < 4; ++t) {
    int col = (int)bn + t * 16 + lrow;
    float bv = HAS_BIAS ? bias[col] : 0.0f;
#pragma unroll
    for (int r = 0; r < 4; ++r) {
      float v = acc[t][r] * alpha + bv;
      if (RELU) v = fmaxf(v, 0.0f);
      if (WF32) Cf[(row0 + r) * (size_t)ldc + col] = v;
      if (WHI) {
        unsigned short h = f2bf(v);
        Chi[(row0 + r) * (size_t)ldcb + col] = h;
        if (WLO) Clo[(row0 + r) * (size_t)ldcb + col] = f2bf(v - bf2f(h));
      }
    }
  }
}

// ---------------- top-4 register insertion ----------------
#define INSERT4(lv, li, v, col)                                   \
  do {                                                            \
    if ((v) > lv[3]) {                                            \
      float cv_ = (v); int ci_ = (col);                           \
      _Pragma("unroll")                                           \
      for (int j_ = 0; j_ < 4; ++j_) {                            \
        bool sw_ = (cv_ > lv[j_]);                                \
        float tv_ = sw_ ? lv[j_] : cv_;                           \
        int ti_ = sw_ ? li[j_] : ci_;                              \
        lv[j_] = sw_ ? cv_ : lv[j_];                              \
        li[j_] = sw_ ? ci_ : li[j_];                              \
        cv_ = tv_; ci_ = ti_;                                     \
      }                                                           \
    }                                                             \
  } while (0)

// ---------------- attention 1: 1 block (4 waves) per row of 16384 ----------
__global__ __launch_bounds__(256) void attn1_kernel(
    const float* __restrict__ dots,          // NE x NN
    const unsigned short* __restrict__ vhi,  // NN x 512 bf16
    unsigned short* __restrict__ e1_hi, unsigned short* __restrict__ e1_lo) {
  __shared__ float sm_m[4], sm_s[4];
  __shared__ unsigned long long wbest[4];
  __shared__ unsigned long long wkey_s[TOPK];

  int tid = threadIdx.x, wave = tid >> 6, lane = tid & 63;
  int rowi = blockIdx.x;
  const float4* r4 = (const float4*)(dots + (size_t)rowi * NN);

  float lv[4]; int li[4];
#pragma unroll
  for (int j = 0; j < 4; ++j) { lv[j] = -INFINITY; li[j] = 0x7fffffff; }
  unsigned long long selmask = 0ull;
  int taken = 0;

  float m_loc = -INFINITY, s_loc = 0.0f;
  for (int i = 0; i < 16; ++i) {
    float4 q = r4[tid + (i << 8)];
#pragma unroll
    for (int c = 0; c < 4; ++c) {
      float v = (&q.x)[c];
      int col = ((tid + (i << 8)) << 2) + c;
      if (v > m_loc) {
        s_loc = s_loc * __expf(m_loc - v) + 1.0f;
        m_loc = v;
      } else {
        s_loc += __expf(v - m_loc);
      }
      INSERT4(lv, li, v, col);
    }
  }
#pragma unroll
  for (int sft = 32; sft; sft >>= 1) {
    float om = __shfl_xor(m_loc, sft, 64);
    float os = __shfl_xor(s_loc, sft, 64);
    float M = fmaxf(m_loc, om);
    s_loc = s_loc * __expf(m_loc - M) + os * __expf(om - M);
    m_loc = M;
  }
  if (lane == 0) { sm_m[wave] = m_loc; sm_s[wave] = s_loc; }
  __syncthreads();
  float M = fmaxf(fmaxf(sm_m[0], sm_m[1]), fmaxf(sm_m[2], sm_m[3]));
  float Z = sm_s[0] * __expf(sm_m[0] - M) + sm_s[1] * __expf(sm_m[1] - M) +
            sm_s[2] * __expf(sm_m[2] - M) + sm_s[3] * __expf(sm_m[3] - M);

  for (int rnd = 0; rnd < TOPK; ++rnd) {
    unsigned long long key;
    if (taken < 4) {
      key = packkc(lv[0], li[0]);
    } else {  // rare: rescan this thread's 64 values from L2, excluding taken
      key = 0ull;
      for (int i = 0; i < 16; ++i) {
        float4 q = r4[tid + (i << 8)];
#pragma unroll
        for (int c = 0; c < 4; ++c) {
          int sl = i * 4 + c;
          if (!((selmask >> sl) & 1ull)) {
            int col = ((tid + (i << 8)) << 2) + c;
            unsigned long long kk = packkc((&q.x)[c], col);
            if (kk > key) key = kk;
          }
        }
      }
    }
#pragma unroll
    for (int sft = 32; sft; sft >>= 1) {
      unsigned long long ok = shfl_xor_u64(key, sft);
      if (ok > key) key = ok;
    }
    if (lane == 0) wbest[wave] = key;
    __syncthreads();
    unsigned long long w = wbest[0];
    if (wbest[1] > w) w = wbest[1];
    if (wbest[2] > w) w = wbest[2];
    if (wbest[3] > w) w = wbest[3];
    if (tid == 0) wkey_s[rnd] = w;
    int wcol = unpack_col(w);
    if (((wcol >> 2) & 255) == tid) {
      int sl = ((wcol >> 10) << 2) | (wcol & 3);
      selmask |= (1ull << sl);
      if (taken < 4) {
#pragma unroll
        for (int j = 0; j < 3; ++j) { lv[j] = lv[j + 1]; li[j] = li[j + 1]; }
      }
      ++taken;
    }
    __syncthreads();
  }

  const float inv_den = 1.0f / (1.0f + (float)NN * EPS_F);
  float invZ = 1.0f / Z;
  float u0 = 0.f, u1 = 0.f;
#pragma unroll
  for (int j = 0; j < TOPK; ++j) {
    unsigned long long w = wkey_s[j];
    int col = unpack_col(w);
    float val = unpack_val(w);
    float a = (__expf(val - M) * invZ + EPS_F) * inv_den;
    const unsigned short* vr = vhi + (size_t)col * 512;
    u0 += a * bf2f(vr[tid]);
    u1 += a * bf2f(vr[tid + 256]);
  }
  size_t o = (size_t)rowi * 1024 + 512;
  unsigned short h0 = f2bf(u0), h1 = f2bf(u1);
  e1_hi[o + tid] = h0;             e1_lo[o + tid] = f2bf(u0 - bf2f(h0));
  e1_hi[o + tid + 256] = h1;       e1_lo[o + tid + 256] = f2bf(u1 - bf2f(h1));
}

// ---------------- attention 2: 1 wave per row of 2048 (4 rows/block) -------
__global__ __launch_bounds__(256) void attn2_kernel(const float* __restrict__ dots2,
                                                    float* __restrict__ Hout) {
  int tid = threadIdx.x, wave = tid >> 6, lane = tid & 63;
  int rowi = blockIdx.x * 4 + wave;
  const float4* r4 = (const float4*)(dots2 + (size_t)rowi * NE);

  float d[32];
  float m = -INFINITY;
#pragma unroll
  for (int i = 0; i < 8; ++i) {
    float4 q = r4[lane + (i << 6)];
#pragma unroll
    for (int c = 0; c < 4; ++c) {
      d[i * 4 + c] = (&q.x)[c];
      m = fmaxf(m, d[i * 4 + c]);
    }
  }
#pragma unroll
  for (int sft = 32; sft; sft >>= 1) m = fmaxf(m, __shfl_xor(m, sft, 64));

  float s = 0.f;
#pragma unroll
  for (int j = 0; j < 32; ++j) { d[j] = __expf(d[j] - m); s += d[j]; }
#pragma unroll
  for (int sft = 32; sft; sft >>= 1) s += __shfl_xor(s, sft, 64);
  float invZ = 1.0f / s;

  float lv[4]; int li[4];
#pragma unroll
  for (int j = 0; j < 4; ++j) { lv[j] = -INFINITY; li[j] = 0x7fffffff; }
#pragma unroll
  for (int i = 0; i < 8; ++i) {
#pragma unroll
    for (int c = 0; c < 4; ++c) {
      int col = ((lane + (i << 6)) << 2) + c;
      INSERT4(lv, li, d[i * 4 + c], col);
    }
  }

  unsigned selmask = 0;
  int taken = 0;
  for (int rnd = 0; rnd < TOPK; ++rnd) {
    unsigned long long key;
    if (taken < 4) {
      key = packkc(lv[0], li[0]);
    } else {
      key = 0ull;
#pragma unroll
      for (int j = 0; j < 32; ++j) {
        if (!((selmask >> j) & 1u)) {
          int col = ((lane + ((j >> 2) << 6)) << 2) + (j & 3);
          unsigned long long kk = packkc(d[j], col);
          if (kk > key) key = kk;
        }
      }
    }
#pragma unroll
    for (int sft = 32; sft; sft >>= 1) {
      unsigned long long ok = shfl_xor_u64(key, sft);
      if (ok > key) key = ok;
    }
    int wcol = unpack_col(key);
    if (((wcol >> 2) & 63) == lane) {
      int sl = ((wcol >> 8) << 2) | (wcol & 3);
      selmask |= (1u << sl);
      if (taken < 4) {
#pragma unroll
        for (int j = 0; j < 3; ++j) { lv[j] = lv[j + 1]; li[j] = li[j + 1]; }
      }
      ++taken;
    }
  }

  float* hr = Hout + (size_t)rowi * NE;
#pragma unroll
  for (int i = 0; i < 8; ++i) {
    float4 o;
#pragma unroll
    for (int c = 0; c < 4; ++c) {
      int sl = i * 4 + c;
      (&o.x)[c] = ((selmask >> sl) & 1u) ? d[sl] * invZ : 0.0f;
    }
    ((float4*)hr)[lane + (i << 6)] = o;
  }
}

// ---------------------------------------------------------------------------
extern "C" void kernel_launch(void* const* d_in, const int* in_sizes, int n_in,
                              void* d_out, int out_size, void* d_ws, size_t ws_size,
                              hipStream_t stream) {
  (void)in_sizes; (void)n_in; (void)out_size; (void)ws_size;
  const float* inputs  = (const float*)d_in[0];
  const float* noise   = (const float*)d_in[1];
  const float* edges_mu = (const float*)d_in[2];
  const float* edges_ls = (const float*)d_in[3];
  const float* Wq = (const float*)d_in[4];
  const float* bq = (const float*)d_in[5];
  const float* Wk = (const float*)d_in[6];
  const float* bk = (const float*)d_in[7];
  const float* Wv = (const float*)d_in[8];
  const float* bv = (const float*)d_in[9];
  const float* W1 = (const float*)d_in[10];
  const float* b1 = (const float*)d_in[11];
  const float* W2 = (const float*)d_in[12];
  const float* b2 = (const float*)d_in[13];
  const float* ln_in_w = (const float*)d_in[14];
  const float* ln_in_b = (const float*)d_in[15];
  const float* ln_e_w = (const float*)d_in[16];
  const float* ln_e_b = (const float*)d_in[17];

  float* out_e  = (float*)d_out;                  // [2048,512]
  float* out_H  = out_e + (size_t)NE * 512;       // [16384,2048]
  float* out_d2 = out_H + (size_t)NN * NE;        // [16384,2048]

  const size_t MB = 1024 * 1024;
  // Scratch in the H output region (dead before attn2 writes H).
  unsigned char* hb = (unsigned char*)out_H;
  unsigned short* x_hi  = (unsigned short*)(hb);                 // 16 MB
  unsigned short* k_hi  = (unsigned short*)(hb + 16 * MB);       // 16 MB
  unsigned short* v_hi  = (unsigned short*)(hb + 32 * MB);       // 16 MB
  unsigned short* q2_hi = (unsigned short*)(hb + 48 * MB);       // 16 MB
  unsigned short* WcatT = (unsigned short*)(hb + 64 * MB);       // 1.5 MB [Wk;Wv;Wq]^T
  unsigned short* W1Th  = (unsigned short*)(hb + 66 * MB);       // 1 MB
  unsigned short* W1Tl  = (unsigned short*)(hb + 67 * MB);       // 1 MB
  unsigned short* W2Th  = (unsigned short*)(hb + 68 * MB);       // 0.5 MB
  unsigned short* W2Tl  = (unsigned short*)(hb + 68 * MB + 512 * 1024);
  unsigned short* e1_hi = (unsigned short*)(hb + 70 * MB);       // 4 MB [2048,1024]
  unsigned short* e1_lo = (unsigned short*)(hb + 74 * MB);       // 4 MB
  unsigned short* q_hi  = (unsigned short*)(hb + 78 * MB);       // 2 MB
  unsigned short* h_hi  = (unsigned short*)(hb + 80 * MB);       // 2 MB
  unsigned short* h_lo  = (unsigned short*)(hb + 82 * MB);       // 2 MB
  unsigned short* e_hi  = (unsigned short*)(hb + 84 * MB);       // 2 MB
  unsigned short* WkT   = WcatT;                                 // slab 0
  unsigned short* WqT   = WcatT + (size_t)1024 * 512;            // slab 2
  // dots fp32 scratch lives in the dots2 output region (consumed by attn1
  // before the dots2 GEMM overwrites the region).
  float* dots = out_d2;
  unsigned short* k2_hi = (unsigned short*)d_ws;                 // 2 MB true ws

  dim3 tb(256);
  dim3 t32(32, 8);

  // weights -> transposed bf16
  transpose_cast3_kernel<<<dim3(16, 16, 3), t32, 0, stream>>>(Wk, Wv, Wq, WcatT);
  transpose_cast_kernel<<<dim3(16, 32), t32, 0, stream>>>(W1, W1Th, W1Tl, 1024, 512);
  transpose_cast_kernel<<<dim3(16, 16), t32, 0, stream>>>(W2, W2Th, W2Tl, 512, 512);

  ln_x_kernel<<<NN, tb, 0, stream>>>(inputs, ln_in_w, ln_in_b, x_hi);
  ln_e_kernel<<<NE, tb, 0, stream>>>(noise, edges_mu, edges_ls, ln_e_w, ln_e_b, e1_hi, e1_lo);

  // k = relu(x@Wk+bk), v = relu(x@Wv+bv), q2 = x@Wq+bq  (one fused GEMM, 256^2/8-phase)
  gemm256_kvq_kernel<<<dim3(384), dim3(512), 0, stream>>>(
      x_hi, WcatT, bk, bv, bq, k_hi, v_hi, q2_hi, 6);
  // q = relu(e0@Wq+bq)
  gemm64_kernel<false, true, true, false, true, false><<<dim3(32, 8), tb, 0, stream>>>(
      e1_hi, nullptr, 1024, WqT, nullptr, 512, bq, 1.f, nullptr, 0, q_hi, nullptr, 512);
  // dots = q@k^T * SCALE -> dots2-region scratch  (256^2/8-phase)
  gemm256_dots_kernel<<<dim3(512), dim3(512), 0, stream>>>(
      q_hi, k_hi, SCALE_F, dots, NN, 64);
  // attn1 -> updates into e1[:,512:]
  attn1_kernel<<<NE, tb, 0, stream>>>(dots, v_hi, e1_hi, e1_lo);
  // h = relu(e1@W1+b1)  (SPLIT)
  gemm64_kernel<true, true, true, false, true, true><<<dim3(32, 8), tb, 0, stream>>>(
      e1_hi, e1_lo, 1024, W1Th, W1Tl, 1024, b1, 1.f, nullptr, 0, h_hi, h_lo, 512);
  // e = h@W2+b2  (SPLIT) -> OUTPUT 0 + bf16 hi
  gemm64_kernel<true, false, true, true, true, false><<<dim3(32, 8), tb, 0, stream>>>(
      h_hi, h_lo, 512, W2Th, W2Tl, 512, b2, 1.f, out_e, 512, e_hi, nullptr, 512);
  // k2 = relu(e@Wk+bk)
  gemm64_kernel<false, true, true, false, true, false><<<dim3(32, 8), tb, 0, stream>>>(
      e_hi, nullptr, 512, WkT, nullptr, 512, bk, 1.f, nullptr, 0, k2_hi, nullptr, 512);
  // dots2 = q2@k2^T * SCALE -> OUTPUT 2  (256^2/8-phase)
  gemm256_dots_kernel<<<dim3(512), dim3(512), 0, stream>>>(
      q2_hi, k2_hi, SCALE_F, out_d2, NE, 8);
  // attn2 -> OUTPUT 1 (H), overwrites all H-region scratch (dead)
  attn2_kernel<<<NN / 4, tb, 0, stream>>>(out_d2, out_H);
}

// Round 3
// 571.315 us; speedup vs baseline: 1.5935x; 1.5935x over previous
//
#include <hip/hip_runtime.h>
#include <stdint.h>

// ---------------------------------------------------------------------------
// HConstructor (slot-attention block) on gfx950.  Round 7 (= round 6 resubmit;
// round 6 died to a container infra failure, no kernel signal).
//   - gemm128 core (bit-identical accumulation vs the 570us round-4 kernel).
//   - Coalesced epilogues via LDS transpose (full-line float4/uint4 stores)
//     for gemm128_dots and gemm128_kvq -> kill 4x write amplification seen in
//     R5 counters (WRITE 516MB vs 128MB output).
//   - XCD-panel tile mapping (each XCD owns a ~2MB operand panel and sweeps
//     the other ~2MB operand -> 4MB working set = per-XCD L2), vs R5's
//     241MB FETCH against 18MB unique input.
//
// Pipeline:
//   x  = LN(inputs)                    [16384,512]  (bf16)
//   e0 = LN(mu + exp(ls)*noise)        [2048,512]   (bf16 hi+lo)
//   {k,v} = relu(x@W{k,v}+b), q2 = x@Wq+bq   (one fused gemm128, N=1536)
//   q = relu(e0@Wq+bq)                              (gemm64)
//   dots = q@k^T * SCALE  -> fp32 scratch in dots2 region
//   attn1: softmax(+eps,renorm), top-10, updates -> e1[:,512:1024]
//   h = relu(e1@W1+b1)   SPLIT bf16 (3-term);  e = h@W2+b2 SPLIT -> OUTPUT 0
//   k2 = relu(e@Wk+bk)
//   dots2 = q2@k2^T*SCALE -> OUTPUT 2;  attn2 -> OUTPUT 1 (H)
// ---------------------------------------------------------------------------

#define NN 16384
#define NE 2048
#define TOPK 10

static const float SCALE_F = 0.04419417382415922f;  // 512^-0.5
#define EPS_F 1e-8f

using bf16x8  = __attribute__((ext_vector_type(8))) __bf16;
using floatx4 = __attribute__((ext_vector_type(4))) float;

__device__ __forceinline__ unsigned f_as_u(float f) {
  union { float f; unsigned u; } v; v.f = f; return v.u;
}
__device__ __forceinline__ float u_as_f(unsigned u) {
  union { unsigned u; float f; } v; v.u = u; return v.f;
}
__device__ __forceinline__ unsigned short f2bf(float f) {
  unsigned u = f_as_u(f);
  unsigned r = u + 0x7fffu + ((u >> 16) & 1u);
  return (unsigned short)(r >> 16);
}
__device__ __forceinline__ float bf2f(unsigned short h) {
  return u_as_f(((unsigned)h) << 16);
}

// async global->LDS, 16 B per lane; LDS dst is wave-uniform base + lane*16
__device__ __forceinline__ void glds16(const unsigned short* g, unsigned short* l) {
  __builtin_amdgcn_global_load_lds(
      (const __attribute__((address_space(1))) unsigned int*)g,
      (__attribute__((address_space(3))) unsigned int*)l, 16, 0, 0);
}

// monotone float->u32 key; pack (value, col) so u64 max = (max val, tie->smaller col)
__device__ __forceinline__ unsigned fkey(float f) {
  unsigned u = f_as_u(f);
  return (u & 0x80000000u) ? ~u : (u | 0x80000000u);
}
__device__ __forceinline__ float funkey(unsigned k) {
  unsigned u = (k & 0x80000000u) ? (k ^ 0x80000000u) : ~k;
  return u_as_f(u);
}
__device__ __forceinline__ unsigned long long packkc(float v, int col) {
  return ((unsigned long long)fkey(v) << 32) | (unsigned)(~(unsigned)col);
}
__device__ __forceinline__ int unpack_col(unsigned long long w) {
  return (int)(~(unsigned)(w & 0xFFFFFFFFull));
}
__device__ __forceinline__ float unpack_val(unsigned long long w) {
  return funkey((unsigned)(w >> 32));
}
__device__ __forceinline__ unsigned long long shfl_xor_u64(unsigned long long x, int m) {
  unsigned lo = (unsigned)x, hi = (unsigned)(x >> 32);
  lo = __shfl_xor(lo, m, 64);
  hi = __shfl_xor(hi, m, 64);
  return ((unsigned long long)hi << 32) | lo;
}

// ---------------- weight transposes ----------------
__global__ void transpose_cast_kernel(const float* __restrict__ src,
                                      unsigned short* __restrict__ dhi,
                                      unsigned short* __restrict__ dlo,
                                      int K, int N) {
  __shared__ float tile[32][33];
  int n0 = blockIdx.x * 32, k0 = blockIdx.y * 32;
  int tx = threadIdx.x, ty = threadIdx.y;  // 32 x 8
  for (int r = ty; r < 32; r += 8)
    tile[r][tx] = src[(size_t)(k0 + r) * N + n0 + tx];
  __syncthreads();
  for (int r = ty; r < 32; r += 8) {
    float v = tile[tx][r];
    size_t o = (size_t)(n0 + r) * K + k0 + tx;
    unsigned short h = f2bf(v);
    dhi[o] = h;
    if (dlo) dlo[o] = f2bf(v - bf2f(h));
  }
}

// three 512x512 weights -> Wcat [1536,512] bf16 (slab order: z=0 Wk, 1 Wv, 2 Wq)
__global__ void transpose_cast3_kernel(const float* __restrict__ s0,
                                       const float* __restrict__ s1,
                                       const float* __restrict__ s2,
                                       unsigned short* __restrict__ dhi) {
  __shared__ float tile[32][33];
  const float* src = blockIdx.z == 0 ? s0 : (blockIdx.z == 1 ? s1 : s2);
  unsigned short* d = dhi + (size_t)blockIdx.z * 512 * 512;
  int n0 = blockIdx.x * 32, k0 = blockIdx.y * 32;
  int tx = threadIdx.x, ty = threadIdx.y;
  for (int r = ty; r < 32; r += 8)
    tile[r][tx] = src[(size_t)(k0 + r) * 512 + n0 + tx];
  __syncthreads();
  for (int r = ty; r < 32; r += 8)
    d[(size_t)(n0 + r) * 512 + k0 + tx] = f2bf(tile[tx][r]);
}

// ---------------- block reduce (256 threads = 4 waves) ----------------
__device__ __forceinline__ float block_sum_256(float v, float* sm4) {
#pragma unroll
  for (int off = 32; off; off >>= 1) v += __shfl_down(v, off, 64);
  __syncthreads();
  if ((threadIdx.x & 63) == 0) sm4[threadIdx.x >> 6] = v;
  __syncthreads();
  return (sm4[0] + sm4[1]) + (sm4[2] + sm4[3]);
}

// ---------------- layernorm kernels ----------------
__global__ __launch_bounds__(256) void ln_x_kernel(
    const float* __restrict__ in, const float* __restrict__ w,
    const float* __restrict__ b, unsigned short* __restrict__ out_hi) {
  __shared__ float sm4[4];
  int row = blockIdx.x, tid = threadIdx.x;
  const float* r = in + (size_t)row * 512;
  float x0 = r[tid], x1 = r[tid + 256];
  float mu = block_sum_256(x0 + x1, sm4) * (1.0f / 512.0f);
  float d0 = x0 - mu, d1 = x1 - mu;
  float var = block_sum_256(d0 * d0 + d1 * d1, sm4) * (1.0f / 512.0f);
  float rs = rsqrtf(var + 1e-5f);
  out_hi[(size_t)row * 512 + tid]       = f2bf(d0 * rs * w[tid] + b[tid]);
  out_hi[(size_t)row * 512 + tid + 256] = f2bf(d1 * rs * w[tid + 256] + b[tid + 256]);
}

__global__ __launch_bounds__(256) void ln_e_kernel(
    const float* __restrict__ noise, const float* __restrict__ mu_e,
    const float* __restrict__ ls_e, const float* __restrict__ w,
    const float* __restrict__ b, unsigned short* __restrict__ e1_hi,
    unsigned short* __restrict__ e1_lo) {
  __shared__ float sm4[4];
  int row = blockIdx.x, tid = threadIdx.x;
  const float* r = noise + (size_t)row * 512;
  float x0 = mu_e[tid] + expf(ls_e[tid]) * r[tid];
  float x1 = mu_e[tid + 256] + expf(ls_e[tid + 256]) * r[tid + 256];
  float mu = block_sum_256(x0 + x1, sm4) * (1.0f / 512.0f);
  float d0 = x0 - mu, d1 = x1 - mu;
  float var = block_sum_256(d0 * d0 + d1 * d1, sm4) * (1.0f / 512.0f);
  float rs = rsqrtf(var + 1e-5f);
  float y0 = d0 * rs * w[tid] + b[tid];
  float y1 = d1 * rs * w[tid + 256] + b[tid + 256];
  size_t o = (size_t)row * 1024;
  unsigned short h0 = f2bf(y0), h1 = f2bf(y1);
  e1_hi[o + tid] = h0;             e1_lo[o + tid] = f2bf(y0 - bf2f(h0));
  e1_hi[o + tid + 256] = h1;       e1_lo[o + tid + 256] = f2bf(y1 - bf2f(h1));
}

// ---------------- gemm128 core: 128x128 tile, K=512 fixed, glds staging ----
// A [M,512], B [N,512] row-major bf16, both row stride 512.
// acc layout: acc[i][t][r] -> C row bm + wave*32 + i*16 + quad*4 + r,
//                             col bn + t*16 + (lane&15)
// SMEM_ is a kernel-declared char array; first 16 KB are used as As/Bs.
#define GEMM128_CORE(A_, B_, bm_, bn_, acc_, SMEM_)                            \
  unsigned short* As = (unsigned short*)(SMEM_);                               \
  unsigned short* Bs = (unsigned short*)(SMEM_) + 4096;                        \
  {                                                                            \
    const unsigned short* gA0 = (A_) + ((bm_) + (tid >> 2)) * 512 + ((tid & 3) << 3); \
    const unsigned short* gA1 = gA0 + 64 * 512;                                \
    const unsigned short* gB0 = (B_) + ((bn_) + (tid >> 2)) * 512 + ((tid & 3) << 3); \
    const unsigned short* gB1 = gB0 + 64 * 512;                                \
    unsigned short* dA0 = &As[wave * 512];                                     \
    unsigned short* dA1 = &As[2048 + wave * 512];                              \
    unsigned short* dB0 = &Bs[wave * 512];                                     \
    unsigned short* dB1 = &Bs[2048 + wave * 512];                              \
    for (int k0 = 0; k0 < 512; k0 += 32) {                                     \
      glds16(gA0 + k0, dA0);                                                   \
      glds16(gA1 + k0, dA1);                                                   \
      glds16(gB0 + k0, dB0);                                                   \
      glds16(gB1 + k0, dB1);                                                   \
      __syncthreads();                                                         \
      bf16x8 af0 = *(const bf16x8*)&As[(wave * 32 + lrow) * 32 + quad * 8];    \
      bf16x8 af1 = *(const bf16x8*)&As[(wave * 32 + 16 + lrow) * 32 + quad * 8]; \
      _Pragma("unroll")                                                        \
      for (int t = 0; t < 8; ++t) {                                            \
        bf16x8 bfr = *(const bf16x8*)&Bs[(t * 16 + lrow) * 32 + quad * 8];     \
        acc_[0][t] = __builtin_amdgcn_mfma_f32_16x16x32_bf16(af0, bfr, acc_[0][t], 0, 0, 0); \
        acc_[1][t] = __builtin_amdgcn_mfma_f32_16x16x32_bf16(af1, bfr, acc_[1][t], 0, 0, 0); \
      }                                                                        \
      __syncthreads();                                                         \
    }                                                                          \
  }

// XCD-panel tile mapping: bid%8 ~ XCD.  The XCD owns a contiguous panel of
// (owns_m ? M : N) tiles (mt resp. nt must be divisible by 8) and sweeps the
// full other dimension -> per-XCD working set = panel(2MB) + swept op tile,
// both L2-resident.  Bijective for any mapping of bid->XCD (perf-only).
#define XCD_PANEL_MAP(mt_, nt_, owns_m_)                                       \
  int bid = (int)blockIdx.x, xcd = bid & 7, idx = bid >> 3;                    \
  int per = ((owns_m_) ? (mt_) : (nt_)) >> 3;                                  \
  int pa = idx % per, pb = idx / per;                                          \
  size_t bm = (size_t)((owns_m_) ? (xcd * per + pa) : pb) * 128;               \
  size_t bn = (size_t)((owns_m_) ? pb : (xcd * per + pa)) * 128;

// dots / dots2: C = alpha * A@B^T (fp32 out), coalesced LDS-staged epilogue.
__global__ __launch_bounds__(256) void gemm128_dots_kernel(
    const unsigned short* __restrict__ A, const unsigned short* __restrict__ B,
    float alpha, float* __restrict__ C, int ldc, int mt, int nt, int owns_m) {
  // 33792 B: As/Bs (16KB) overlaid with the epilogue buffer [4][16][132] fp32
  __shared__ __align__(16) char smem[33792];
  int tid = threadIdx.x, wave = tid >> 6, lane = tid & 63;
  int lrow = lane & 15, quad = lane >> 4;
  XCD_PANEL_MAP(mt, nt, owns_m)
  floatx4 zero4 = {0.f, 0.f, 0.f, 0.f};
  floatx4 acc[2][8];
#pragma unroll
  for (int i = 0; i < 2; ++i)
#pragma unroll
    for (int t = 0; t < 8; ++t) acc[i][t] = zero4;
  GEMM128_CORE(A, B, bm, bn, acc, smem)
  // epilogue: per-wave 16x128 fp32 staging, then full-line float4 stores
  __syncthreads();
  float* wb = (float*)smem + wave * (16 * 132);
#pragma unroll
  for (int i = 0; i < 2; ++i) {
#pragma unroll
    for (int t = 0; t < 8; ++t)
#pragma unroll
      for (int r = 0; r < 4; ++r)
        wb[(quad * 4 + r) * 132 + t * 16 + lrow] = acc[i][t][r] * alpha;
    __syncthreads();
    size_t rowbase = bm + wave * 32 + i * 16;
#pragma unroll
    for (int p = 0; p < 8; ++p) {
      int rr = p * 2 + (lane >> 5);
      float4 v = *(const float4*)&wb[rr * 132 + ((lane & 31) << 2)];
      *(float4*)&C[(rowbase + rr) * (size_t)ldc + bn + ((lane & 31) << 2)] = v;
    }
    __syncthreads();
  }
}

// fused k/v/q2: A = x [16384,512]; B = Wcat [1536,512] (slabs: Wk, Wv, Wq).
// block col slab: bn>>9 -> 0:k (relu), 1:v (relu), 2:q2 (no relu). All ld 512.
__global__ __launch_bounds__(256) void gemm128_kvq_kernel(
    const unsigned short* __restrict__ A, const unsigned short* __restrict__ B,
    const float* __restrict__ bk, const float* __restrict__ bv,
    const float* __restrict__ bq,
    unsigned short* __restrict__ khi, unsigned short* __restrict__ vhi,
    unsigned short* __restrict__ q2hi) {
  // 17408 B: As/Bs (16KB) overlaid with epilogue buffer [4][16][136] bf16
  __shared__ __align__(16) char smem[17408];
  int tid = threadIdx.x, wave = tid >> 6, lane = tid & 63;
  int lrow = lane & 15, quad = lane >> 4;
  XCD_PANEL_MAP(128, 12, 1)
  floatx4 zero4 = {0.f, 0.f, 0.f, 0.f};
  floatx4 acc[2][8];
#pragma unroll
  for (int i = 0; i < 2; ++i)
#pragma unroll
    for (int t = 0; t < 8; ++t) acc[i][t] = zero4;
  GEMM128_CORE(A, B, bm, bn, acc, smem)
  int mat = (int)(bn >> 9);
  int colbase = (int)(bn & 511);
  const float* bias = mat == 0 ? bk : (mat == 1 ? bv : bq);
  unsigned short* dst = mat == 0 ? khi : (mat == 1 ? vhi : q2hi);
  bool relu = mat < 2;
  __syncthreads();
  unsigned short* wb = (unsigned short*)smem + wave * (16 * 136);
#pragma unroll
  for (int i = 0; i < 2; ++i) {
#pragma unroll
    for (int t = 0; t < 8; ++t) {
      float bvv = bias[colbase + t * 16 + lrow];
#pragma unroll
      for (int r = 0; r < 4; ++r) {
        float v = acc[i][t][r] + bvv;
        if (relu) v = fmaxf(v, 0.0f);
        wb[(quad * 4 + r) * 136 + t * 16 + lrow] = f2bf(v);
      }
    }
    __syncthreads();
    size_t rowbase = bm + wave * 32 + i * 16;
#pragma unroll
    for (int p = 0; p < 4; ++p) {
      int rr = p * 4 + (lane >> 4);
      uint4 v = *(const uint4*)&wb[rr * 136 + ((lane & 15) << 3)];
      *(uint4*)&dst[(rowbase + rr) * 512 + colbase + ((lane & 15) << 3)] = v;
    }
    __syncthreads();
  }
}

// ---------------- GEMM, 64x64 tile, optional 3-term hi/lo split ----------------
template <bool SPLIT, bool RELU, bool HAS_BIAS, bool WF32, bool WHI, bool WLO>
__global__ __launch_bounds__(256) void gemm64_kernel(
    const unsigned short* __restrict__ Ahi, const unsigned short* __restrict__ Alo, int lda,
    const unsigned short* __restrict__ Bhi, const unsigned short* __restrict__ Blo, int K,
    const float* __restrict__ bias, float alpha,
    float* __restrict__ Cf, int ldc,
    unsigned short* __restrict__ Chi, unsigned short* __restrict__ Clo, int ldcb) {
  __shared__ __align__(16) unsigned short AsH[64 * 32];
  __shared__ __align__(16) unsigned short BsH[64 * 32];
  __shared__ __align__(16) unsigned short AsL[64 * 32];
  __shared__ __align__(16) unsigned short BsL[64 * 32];
  int tid = threadIdx.x, wave = tid >> 6, lane = tid & 63;
  int lrow = lane & 15, quad = lane >> 4;
  size_t bm = (size_t)blockIdx.x * 64, bn = (size_t)blockIdx.y * 64;
  int row = tid >> 2, off = (tid & 3) << 3;
  size_t aoff = (bm + row) * (size_t)lda + off;
  size_t boff = (bn + row) * (size_t)K + off;

  floatx4 zero4 = {0.f, 0.f, 0.f, 0.f};
  floatx4 acc[4];
#pragma unroll
  for (int t = 0; t < 4; ++t) acc[t] = zero4;

  for (int k0 = 0; k0 < K; k0 += 32) {
    uint4 ah = *(const uint4*)(Ahi + aoff + k0);
    uint4 bh = *(const uint4*)(Bhi + boff + k0);
    uint4 al, bl;
    if (SPLIT) {
      al = *(const uint4*)(Alo + aoff + k0);
      bl = *(const uint4*)(Blo + boff + k0);
    }
    __syncthreads();
    *(uint4*)&AsH[tid * 8] = ah;
    *(uint4*)&BsH[tid * 8] = bh;
    if (SPLIT) {
      *(uint4*)&AsL[tid * 8] = al;
      *(uint4*)&BsL[tid * 8] = bl;
    }
    __syncthreads();
    int ai = (wave * 16 + lrow) * 32 + quad * 8;
    bf16x8 aH = *(const bf16x8*)&AsH[ai];
    bf16x8 aL;
    if (SPLIT) aL = *(const bf16x8*)&AsL[ai];
#pragma unroll
    for (int t = 0; t < 4; ++t) {
      int bi = (t * 16 + lrow) * 32 + quad * 8;
      bf16x8 bH = *(const bf16x8*)&BsH[bi];
      acc[t] = __builtin_amdgcn_mfma_f32_16x16x32_bf16(aH, bH, acc[t], 0, 0, 0);
      if (SPLIT) {
        bf16x8 bL = *(const bf16x8*)&BsL[bi];
        acc[t] = __builtin_amdgcn_mfma_f32_16x16x32_bf16(aH, bL, acc[t], 0, 0, 0);
        acc[t] = __builtin_amdgcn_mfma_f32_16x16x32_bf16(aL, bH, acc[t], 0, 0, 0);
      }
    }
  }
  size_t row0 = bm + wave * 16 + quad * 4;
#pragma unroll
  for (int t = 0; t < 4; ++t) {
    int col = (int)bn + t * 16 + lrow;
    float bv = HAS_BIAS ? bias[col] : 0.0f;
#pragma unroll
    for (int r = 0; r < 4; ++r) {
      float v = acc[t][r] * alpha + bv;
      if (RELU) v = fmaxf(v, 0.0f);
      if (WF32) Cf[(row0 + r) * (size_t)ldc + col] = v;
      if (WHI) {
        unsigned short h = f2bf(v);
        Chi[(row0 + r) * (size_t)ldcb + col] = h;
        if (WLO) Clo[(row0 + r) * (size_t)ldcb + col] = f2bf(v - bf2f(h));
      }
    }
  }
}

// ---------------- top-4 register insertion ----------------
#define INSERT4(lv, li, v, col)                                   \
  do {                                                            \
    if ((v) > lv[3]) {                                            \
      float cv_ = (v); int ci_ = (col);                           \
      _Pragma("unroll")                                           \
      for (int j_ = 0; j_ < 4; ++j_) {                            \
        bool sw_ = (cv_ > lv[j_]);                                \
        float tv_ = sw_ ? lv[j_] : cv_;                           \
        int ti_ = sw_ ? li[j_] : ci_;                              \
        lv[j_] = sw_ ? cv_ : lv[j_];                              \
        li[j_] = sw_ ? ci_ : li[j_];                              \
        cv_ = tv_; ci_ = ti_;                                     \
      }                                                           \
    }                                                             \
  } while (0)

// ---------------- attention 1: 1 block (4 waves) per row of 16384 ----------
__global__ __launch_bounds__(256) void attn1_kernel(
    const float* __restrict__ dots,          // NE x NN
    const unsigned short* __restrict__ vhi,  // NN x 512 bf16
    unsigned short* __restrict__ e1_hi, unsigned short* __restrict__ e1_lo) {
  __shared__ float sm_m[4], sm_s[4];
  __shared__ unsigned long long wbest[4];
  __shared__ unsigned long long wkey_s[TOPK];

  int tid = threadIdx.x, wave = tid >> 6, lane = tid & 63;
  int rowi = blockIdx.x;
  const float4* r4 = (const float4*)(dots + (size_t)rowi * NN);

  float lv[4]; int li[4];
#pragma unroll
  for (int j = 0; j < 4; ++j) { lv[j] = -INFINITY; li[j] = 0x7fffffff; }
  unsigned long long selmask = 0ull;
  int taken = 0;

  float m_loc = -INFINITY, s_loc = 0.0f;
  for (int i = 0; i < 16; ++i) {
    float4 q = r4[tid + (i << 8)];
#pragma unroll
    for (int c = 0; c < 4; ++c) {
      float v = (&q.x)[c];
      int col = ((tid + (i << 8)) << 2) + c;
      if (v > m_loc) {
        s_loc = s_loc * __expf(m_loc - v) + 1.0f;
        m_loc = v;
      } else {
        s_loc += __expf(v - m_loc);
      }
      INSERT4(lv, li, v, col);
    }
  }
#pragma unroll
  for (int sft = 32; sft; sft >>= 1) {
    float om = __shfl_xor(m_loc, sft, 64);
    float os = __shfl_xor(s_loc, sft, 64);
    float M = fmaxf(m_loc, om);
    s_loc = s_loc * __expf(m_loc - M) + os * __expf(om - M);
    m_loc = M;
  }
  if (lane == 0) { sm_m[wave] = m_loc; sm_s[wave] = s_loc; }
  __syncthreads();
  float M = fmaxf(fmaxf(sm_m[0], sm_m[1]), fmaxf(sm_m[2], sm_m[3]));
  float Z = sm_s[0] * __expf(sm_m[0] - M) + sm_s[1] * __expf(sm_m[1] - M) +
            sm_s[2] * __expf(sm_m[2] - M) + sm_s[3] * __expf(sm_m[3] - M);

  for (int rnd = 0; rnd < TOPK; ++rnd) {
    unsigned long long key;
    if (taken < 4) {
      key = packkc(lv[0], li[0]);
    } else {  // rare: rescan this thread's 64 values from L2, excluding taken
      key = 0ull;
      for (int i = 0; i < 16; ++i) {
        float4 q = r4[tid + (i << 8)];
#pragma unroll
        for (int c = 0; c < 4; ++c) {
          int sl = i * 4 + c;
          if (!((selmask >> sl) & 1ull)) {
            int col = ((tid + (i << 8)) << 2) + c;
            unsigned long long kk = packkc((&q.x)[c], col);
            if (kk > key) key = kk;
          }
        }
      }
    }
#pragma unroll
    for (int sft = 32; sft; sft >>= 1) {
      unsigned long long ok = shfl_xor_u64(key, sft);
      if (ok > key) key = ok;
    }
    if (lane == 0) wbest[wave] = key;
    __syncthreads();
    unsigned long long w = wbest[0];
    if (wbest[1] > w) w = wbest[1];
    if (wbest[2] > w) w = wbest[2];
    if (wbest[3] > w) w = wbest[3];
    if (tid == 0) wkey_s[rnd] = w;
    int wcol = unpack_col(w);
    if (((wcol >> 2) & 255) == tid) {
      int sl = ((wcol >> 10) << 2) | (wcol & 3);
      selmask |= (1ull << sl);
      if (taken < 4) {
#pragma unroll
        for (int j = 0; j < 3; ++j) { lv[j] = lv[j + 1]; li[j] = li[j + 1]; }
      }
      ++taken;
    }
    __syncthreads();
  }

  const float inv_den = 1.0f / (1.0f + (float)NN * EPS_F);
  float invZ = 1.0f / Z;
  float u0 = 0.f, u1 = 0.f;
#pragma unroll
  for (int j = 0; j < TOPK; ++j) {
    unsigned long long w = wkey_s[j];
    int col = unpack_col(w);
    float val = unpack_val(w);
    float a = (__expf(val - M) * invZ + EPS_F) * inv_den;
    const unsigned short* vr = vhi + (size_t)col * 512;
    u0 += a * bf2f(vr[tid]);
    u1 += a * bf2f(vr[tid + 256]);
  }
  size_t o = (size_t)rowi * 1024 + 512;
  unsigned short h0 = f2bf(u0), h1 = f2bf(u1);
  e1_hi[o + tid] = h0;             e1_lo[o + tid] = f2bf(u0 - bf2f(h0));
  e1_hi[o + tid + 256] = h1;       e1_lo[o + tid + 256] = f2bf(u1 - bf2f(h1));
}

// ---------------- attention 2: 1 wave per row of 2048 (4 rows/block) -------
__global__ __launch_bounds__(256) void attn2_kernel(const float* __restrict__ dots2,
                                                    float* __restrict__ Hout) {
  int tid = threadIdx.x, wave = tid >> 6, lane = tid & 63;
  int rowi = blockIdx.x * 4 + wave;
  const float4* r4 = (const float4*)(dots2 + (size_t)rowi * NE);

  float d[32];
  float m = -INFINITY;
#pragma unroll
  for (int i = 0; i < 8; ++i) {
    float4 q = r4[lane + (i << 6)];
#pragma unroll
    for (int c = 0; c < 4; ++c) {
      d[i * 4 + c] = (&q.x)[c];
      m = fmaxf(m, d[i * 4 + c]);
    }
  }
#pragma unroll
  for (int sft = 32; sft; sft >>= 1) m = fmaxf(m, __shfl_xor(m, sft, 64));

  float s = 0.f;
#pragma unroll
  for (int j = 0; j < 32; ++j) { d[j] = __expf(d[j] - m); s += d[j]; }
#pragma unroll
  for (int sft = 32; sft; sft >>= 1) s += __shfl_xor(s, sft, 64);
  float invZ = 1.0f / s;

  float lv[4]; int li[4];
#pragma unroll
  for (int j = 0; j < 4; ++j) { lv[j] = -INFINITY; li[j] = 0x7fffffff; }
#pragma unroll
  for (int i = 0; i < 8; ++i) {
#pragma unroll
    for (int c = 0; c < 4; ++c) {
      int col = ((lane + (i << 6)) << 2) + c;
      INSERT4(lv, li, d[i * 4 + c], col);
    }
  }

  unsigned selmask = 0;
  int taken = 0;
  for (int rnd = 0; rnd < TOPK; ++rnd) {
    unsigned long long key;
    if (taken < 4) {
      key = packkc(lv[0], li[0]);
    } else {
      key = 0ull;
#pragma unroll
      for (int j = 0; j < 32; ++j) {
        if (!((selmask >> j) & 1u)) {
          int col = ((lane + ((j >> 2) << 6)) << 2) + (j & 3);
          unsigned long long kk = packkc(d[j], col);
          if (kk > key) key = kk;
        }
      }
    }
#pragma unroll
    for (int sft = 32; sft; sft >>= 1) {
      unsigned long long ok = shfl_xor_u64(key, sft);
      if (ok > key) key = ok;
    }
    int wcol = unpack_col(key);
    if (((wcol >> 2) & 63) == lane) {
      int sl = ((wcol >> 8) << 2) | (wcol & 3);
      selmask |= (1u << sl);
      if (taken < 4) {
#pragma unroll
        for (int j = 0; j < 3; ++j) { lv[j] = lv[j + 1]; li[j] = li[j + 1]; }
      }
      ++taken;
    }
  }

  float* hr = Hout + (size_t)rowi * NE;
#pragma unroll
  for (int i = 0; i < 8; ++i) {
    float4 o;
#pragma unroll
    for (int c = 0; c < 4; ++c) {
      int sl = i * 4 + c;
      (&o.x)[c] = ((selmask >> sl) & 1u) ? d[sl] * invZ : 0.0f;
    }
    ((float4*)hr)[lane + (i << 6)] = o;
  }
}

// ---------------------------------------------------------------------------
extern "C" void kernel_launch(void* const* d_in, const int* in_sizes, int n_in,
                              void* d_out, int out_size, void* d_ws, size_t ws_size,
                              hipStream_t stream) {
  (void)in_sizes; (void)n_in; (void)out_size; (void)ws_size;
  const float* inputs  = (const float*)d_in[0];
  const float* noise   = (const float*)d_in[1];
  const float* edges_mu = (const float*)d_in[2];
  const float* edges_ls = (const float*)d_in[3];
  const float* Wq = (const float*)d_in[4];
  const float* bq = (const float*)d_in[5];
  const float* Wk = (const float*)d_in[6];
  const float* bk = (const float*)d_in[7];
  const float* Wv = (const float*)d_in[8];
  const float* bv = (const float*)d_in[9];
  const float* W1 = (const float*)d_in[10];
  const float* b1 = (const float*)d_in[11];
  const float* W2 = (const float*)d_in[12];
  const float* b2 = (const float*)d_in[13];
  const float* ln_in_w = (const float*)d_in[14];
  const float* ln_in_b = (const float*)d_in[15];
  const float* ln_e_w = (const float*)d_in[16];
  const float* ln_e_b = (const float*)d_in[17];

  float* out_e  = (float*)d_out;                  // [2048,512]
  float* out_H  = out_e + (size_t)NE * 512;       // [16384,2048]
  float* out_d2 = out_H + (size_t)NN * NE;        // [16384,2048]

  const size_t MB = 1024 * 1024;
  // Scratch in the H output region (dead before attn2 writes H).
  unsigned char* hb = (unsigned char*)out_H;
  unsigned short* x_hi  = (unsigned short*)(hb);                 // 16 MB
  unsigned short* k_hi  = (unsigned short*)(hb + 16 * MB);       // 16 MB
  unsigned short* v_hi  = (unsigned short*)(hb + 32 * MB);       // 16 MB
  unsigned short* q2_hi = (unsigned short*)(hb + 48 * MB);       // 16 MB
  unsigned short* WcatT = (unsigned short*)(hb + 64 * MB);       // 1.5 MB [Wk;Wv;Wq]^T
  unsigned short* W1Th  = (unsigned short*)(hb + 66 * MB);       // 1 MB
  unsigned short* W1Tl  = (unsigned short*)(hb + 67 * MB);       // 1 MB
  unsigned short* W2Th  = (unsigned short*)(hb + 68 * MB);       // 0.5 MB
  unsigned short* W2Tl  = (unsigned short*)(hb + 68 * MB + 512 * 1024);
  unsigned short* e1_hi = (unsigned short*)(hb + 70 * MB);       // 4 MB [2048,1024]
  unsigned short* e1_lo = (unsigned short*)(hb + 74 * MB);       // 4 MB
  unsigned short* q_hi  = (unsigned short*)(hb + 78 * MB);       // 2 MB
  unsigned short* h_hi  = (unsigned short*)(hb + 80 * MB);       // 2 MB
  unsigned short* h_lo  = (unsigned short*)(hb + 82 * MB);       // 2 MB
  unsigned short* e_hi  = (unsigned short*)(hb + 84 * MB);       // 2 MB
  unsigned short* WkT   = WcatT;                                 // slab 0
  unsigned short* WqT   = WcatT + (size_t)1024 * 512;            // slab 2
  // dots fp32 scratch lives in the dots2 output region (consumed by attn1
  // before the dots2 GEMM overwrites the region).
  float* dots = out_d2;
  unsigned short* k2_hi = (unsigned short*)d_ws;                 // 2 MB true ws

  dim3 tb(256);
  dim3 t32(32, 8);

  // weights -> transposed bf16
  transpose_cast3_kernel<<<dim3(16, 16, 3), t32, 0, stream>>>(Wk, Wv, Wq, WcatT);
  transpose_cast_kernel<<<dim3(16, 32), t32, 0, stream>>>(W1, W1Th, W1Tl, 1024, 512);
  transpose_cast_kernel<<<dim3(16, 16), t32, 0, stream>>>(W2, W2Th, W2Tl, 512, 512);

  ln_x_kernel<<<NN, tb, 0, stream>>>(inputs, ln_in_w, ln_in_b, x_hi);
  ln_e_kernel<<<NE, tb, 0, stream>>>(noise, edges_mu, edges_ls, ln_e_w, ln_e_b, e1_hi, e1_lo);

  // k = relu(x@Wk+bk), v = relu(x@Wv+bv), q2 = x@Wq+bq  (one fused GEMM)
  // XCD panel: each XCD owns 16 M-tiles (2MB of x), sweeps Wcat (1.5MB).
  gemm128_kvq_kernel<<<dim3(1536), tb, 0, stream>>>(
      x_hi, WcatT, bk, bv, bq, k_hi, v_hi, q2_hi);
  // q = relu(e0@Wq+bq)
  gemm64_kernel<false, true, true, false, true, false><<<dim3(32, 8), tb, 0, stream>>>(
      e1_hi, nullptr, 1024, WqT, nullptr, 512, bq, 1.f, nullptr, 0, q_hi, nullptr, 512);
  // dots = q@k^T * SCALE -> dots2-region scratch
  // XCD panel on N (k rows): each XCD owns 16 N-tiles (2MB of k), sweeps q (2MB).
  gemm128_dots_kernel<<<dim3(2048), tb, 0, stream>>>(
      q_hi, k_hi, SCALE_F, dots, NN, 16, 128, 0);
  // attn1 -> updates into e1[:,512:]
  attn1_kernel<<<NE, tb, 0, stream>>>(dots, v_hi, e1_hi, e1_lo);
  // h = relu(e1@W1+b1)  (SPLIT)
  gemm64_kernel<true, true, true, false, true, true><<<dim3(32, 8), tb, 0, stream>>>(
      e1_hi, e1_lo, 1024, W1Th, W1Tl, 1024, b1, 1.f, nullptr, 0, h_hi, h_lo, 512);
  // e = h@W2+b2  (SPLIT) -> OUTPUT 0 + bf16 hi
  gemm64_kernel<true, false, true, true, true, false><<<dim3(32, 8), tb, 0, stream>>>(
      h_hi, h_lo, 512, W2Th, W2Tl, 512, b2, 1.f, out_e, 512, e_hi, nullptr, 512);
  // k2 = relu(e@Wk+bk)
  gemm64_kernel<false, true, true, false, true, false><<<dim3(32, 8), tb, 0, stream>>>(
      e_hi, nullptr, 512, WkT, nullptr, 512, bk, 1.f, nullptr, 0, k2_hi, nullptr, 512);
  // dots2 = q2@k2^T * SCALE -> OUTPUT 2 (overwrites dots scratch, already consumed)
  // XCD panel on M (q2 rows): each XCD owns 16 M-tiles (2MB of q2), sweeps k2 (2MB).
  gemm128_dots_kernel<<<dim3(2048), tb, 0, stream>>>(
      q2_hi, k2_hi, SCALE_F, out_d2, NE, 128, 16, 1);
  // attn2 -> OUTPUT 1 (H), overwrites all H-region scratch (dead)
  attn2_kernel<<<NN / 4, tb, 0, stream>>>(out_d2, out_H);
}

// Round 4
// 547.194 us; speedup vs baseline: 1.6637x; 1.0441x over previous
//
#include <hip/hip_runtime.h>
#include <stdint.h>

// ---------------------------------------------------------------------------
// HConstructor (slot-attention block) on gfx950.  Round 8:
//   - gemm128 core upgraded to BK=64 (8 K-steps instead of 16 -> half the
//     barrier drains) with XOR-swizzled LDS (granule ^= row&7) applied on
//     BOTH sides: pre-swizzled global_load_lds source + swizzled ds_read.
//     Accumulation order unchanged -> bit-identical outputs.
//   - Launch compaction 14 -> 10 kernels: 3 transposes merged into 1;
//     ln_x+ln_e merged; q-GEMM folded into the kvq launch as extra blocks
//     (independent work, same Wcat B-operand, slab 2).
//   - gemm64 (W1/W2/k2): register-prefetch of next K-chunk before MFMA.
//
// Pipeline:
//   x  = LN(inputs); e0 = LN(mu + exp(ls)*noise)
//   {k,v,q2} = x@Wcat (+q = relu(e0@Wq) fused in same launch)
//   dots = q@k^T*SCALE -> fp32 scratch; attn1 -> updates
//   h = relu(e1@W1+b1) SPLIT; e = h@W2+b2 SPLIT -> OUTPUT 0
//   k2 = relu(e@Wk+bk); dots2 = q2@k2^T*SCALE -> OUTPUT 2; attn2 -> OUTPUT 1
// ---------------------------------------------------------------------------

#define NN 16384
#define NE 2048
#define TOPK 10

static const float SCALE_F = 0.04419417382415922f;  // 512^-0.5
#define EPS_F 1e-8f

using bf16x8  = __attribute__((ext_vector_type(8))) __bf16;
using floatx4 = __attribute__((ext_vector_type(4))) float;

__device__ __forceinline__ unsigned f_as_u(float f) {
  union { float f; unsigned u; } v; v.f = f; return v.u;
}
__device__ __forceinline__ float u_as_f(unsigned u) {
  union { unsigned u; float f; } v; v.u = u; return v.f;
}
__device__ __forceinline__ unsigned short f2bf(float f) {
  unsigned u = f_as_u(f);
  unsigned r = u + 0x7fffu + ((u >> 16) & 1u);
  return (unsigned short)(r >> 16);
}
__device__ __forceinline__ float bf2f(unsigned short h) {
  return u_as_f(((unsigned)h) << 16);
}

// async global->LDS, 16 B per lane; LDS dst is wave-uniform base + lane*16
__device__ __forceinline__ void glds16(const unsigned short* g, unsigned short* l) {
  __builtin_amdgcn_global_load_lds(
      (const __attribute__((address_space(1))) unsigned int*)g,
      (__attribute__((address_space(3))) unsigned int*)l, 16, 0, 0);
}

// monotone float->u32 key; pack (value, col) so u64 max = (max val, tie->smaller col)
__device__ __forceinline__ unsigned fkey(float f) {
  unsigned u = f_as_u(f);
  return (u & 0x80000000u) ? ~u : (u | 0x80000000u);
}
__device__ __forceinline__ float funkey(unsigned k) {
  unsigned u = (k & 0x80000000u) ? (k ^ 0x80000000u) : ~k;
  return u_as_f(u);
}
__device__ __forceinline__ unsigned long long packkc(float v, int col) {
  return ((unsigned long long)fkey(v) << 32) | (unsigned)(~(unsigned)col);
}
__device__ __forceinline__ int unpack_col(unsigned long long w) {
  return (int)(~(unsigned)(w & 0xFFFFFFFFull));
}
__device__ __forceinline__ float unpack_val(unsigned long long w) {
  return funkey((unsigned)(w >> 32));
}
__device__ __forceinline__ unsigned long long shfl_xor_u64(unsigned long long x, int m) {
  unsigned lo = (unsigned)x, hi = (unsigned)(x >> 32);
  lo = __shfl_xor(lo, m, 64);
  hi = __shfl_xor(hi, m, 64);
  return ((unsigned long long)hi << 32) | lo;
}

// ---------------- merged weight transpose ----------------
// z 0..2: Wk/Wv/Wq -> WcatT slab z (512x512, hi only)
// z == 3: W1 -> W1Th/W1Tl   (K=1024, N=512)
// z == 4: W2 -> W2Th/W2Tl   (K=512,  N=512)
__global__ void transpose_all_kernel(
    const float* __restrict__ Wk, const float* __restrict__ Wv,
    const float* __restrict__ Wq, unsigned short* __restrict__ WcatT,
    const float* __restrict__ W1, unsigned short* __restrict__ W1Th,
    unsigned short* __restrict__ W1Tl,
    const float* __restrict__ W2, unsigned short* __restrict__ W2Th,
    unsigned short* __restrict__ W2Tl) {
  __shared__ float tile[32][33];
  int z = blockIdx.z;
  if (z != 3 && blockIdx.y >= 16) return;
  const float* src;
  unsigned short* dhi;
  unsigned short* dlo;
  int K;
  if (z < 3) {
    src = z == 0 ? Wk : (z == 1 ? Wv : Wq);
    dhi = WcatT + (size_t)z * 512 * 512;
    dlo = nullptr; K = 512;
  } else if (z == 3) {
    src = W1; dhi = W1Th; dlo = W1Tl; K = 1024;
  } else {
    src = W2; dhi = W2Th; dlo = W2Tl; K = 512;
  }
  int n0 = blockIdx.x * 32, k0 = blockIdx.y * 32;
  int tx = threadIdx.x, ty = threadIdx.y;  // 32 x 8
  for (int r = ty; r < 32; r += 8)
    tile[r][tx] = src[(size_t)(k0 + r) * 512 + n0 + tx];
  __syncthreads();
  for (int r = ty; r < 32; r += 8) {
    float v = tile[tx][r];
    size_t o = (size_t)(n0 + r) * K + k0 + tx;
    unsigned short h = f2bf(v);
    dhi[o] = h;
    if (dlo) dlo[o] = f2bf(v - bf2f(h));
  }
}

// ---------------- block reduce (256 threads = 4 waves) ----------------
__device__ __forceinline__ float block_sum_256(float v, float* sm4) {
#pragma unroll
  for (int off = 32; off; off >>= 1) v += __shfl_down(v, off, 64);
  __syncthreads();
  if ((threadIdx.x & 63) == 0) sm4[threadIdx.x >> 6] = v;
  __syncthreads();
  return (sm4[0] + sm4[1]) + (sm4[2] + sm4[3]);
}

// ---------------- merged layernorm: blocks [0,NN) = x rows, [NN,NN+NE) = e rows
__global__ __launch_bounds__(256) void ln_all_kernel(
    const float* __restrict__ in, const float* __restrict__ w,
    const float* __restrict__ b, unsigned short* __restrict__ out_hi,
    const float* __restrict__ noise, const float* __restrict__ mu_e,
    const float* __restrict__ ls_e, const float* __restrict__ we,
    const float* __restrict__ be, unsigned short* __restrict__ e1_hi,
    unsigned short* __restrict__ e1_lo) {
  __shared__ float sm4[4];
  int row = blockIdx.x, tid = threadIdx.x;
  if (row < NN) {
    const float* r = in + (size_t)row * 512;
    float x0 = r[tid], x1 = r[tid + 256];
    float mu = block_sum_256(x0 + x1, sm4) * (1.0f / 512.0f);
    float d0 = x0 - mu, d1 = x1 - mu;
    float var = block_sum_256(d0 * d0 + d1 * d1, sm4) * (1.0f / 512.0f);
    float rs = rsqrtf(var + 1e-5f);
    out_hi[(size_t)row * 512 + tid]       = f2bf(d0 * rs * w[tid] + b[tid]);
    out_hi[(size_t)row * 512 + tid + 256] = f2bf(d1 * rs * w[tid + 256] + b[tid + 256]);
  } else {
    row -= NN;
    const float* r = noise + (size_t)row * 512;
    float x0 = mu_e[tid] + expf(ls_e[tid]) * r[tid];
    float x1 = mu_e[tid + 256] + expf(ls_e[tid + 256]) * r[tid + 256];
    float mu = block_sum_256(x0 + x1, sm4) * (1.0f / 512.0f);
    float d0 = x0 - mu, d1 = x1 - mu;
    float var = block_sum_256(d0 * d0 + d1 * d1, sm4) * (1.0f / 512.0f);
    float rs = rsqrtf(var + 1e-5f);
    float y0 = d0 * rs * we[tid] + be[tid];
    float y1 = d1 * rs * we[tid + 256] + be[tid + 256];
    size_t o = (size_t)row * 1024;
    unsigned short h0 = f2bf(y0), h1 = f2bf(y1);
    e1_hi[o + tid] = h0;             e1_lo[o + tid] = f2bf(y0 - bf2f(h0));
    e1_hi[o + tid + 256] = h1;       e1_lo[o + tid + 256] = f2bf(y1 - bf2f(h1));
  }
}

// ---------------- gemm128 core: 128x128 tile, K=512, BK=64, swizzled LDS ---
// A [M,512-or-1024] (runtime lda), B [N,512] row-major bf16.
// LDS layout: row r (0..127) at shorts r*64; 16B granule g within row holds
// global K-chunk ((g ^ (r&7))*8).  Staged via glds16 with pre-swizzled
// global source (linear LDS dest = rule #21).  Read side applies same XOR.
// acc layout: acc[i][t][r] -> C row bm + wave*32 + i*16 + quad*4 + r,
//                             col bn + t*16 + (lane&15)
// Accumulation order per acc element: k0, k0+32 (identical to BK=32 form).
#define GEMM128_CORE(A_, LDA_, B_, bm_, bn_, acc_, SMEM_)                      \
  unsigned short* As = (unsigned short*)(SMEM_);                               \
  unsigned short* Bs = (unsigned short*)(SMEM_) + 8192;                        \
  {                                                                            \
    int srow = tid >> 3;                                                       \
    int scol = ((tid ^ (tid >> 3)) & 7) << 3;                                  \
    const unsigned short* gA = (A_) + ((bm_) + srow) * (size_t)(LDA_) + scol;  \
    const unsigned short* gB = (B_) + ((bn_) + srow) * (size_t)512 + scol;     \
    unsigned short* dA = As + wave * 512;                                      \
    unsigned short* dB = Bs + wave * 512;                                      \
    int swz0 = (quad ^ (lrow & 7)) << 3;                                       \
    int swz1 = swz0 ^ 32;                                                      \
    int aoff0 = (wave * 32 + lrow) * 64;                                       \
    int aoff1 = aoff0 + 16 * 64;                                               \
    int boffl = lrow * 64;                                                     \
    for (int k0 = 0; k0 < 512; k0 += 64) {                                     \
      glds16(gA + k0, dA);                                                     \
      glds16(gA + 32 * (size_t)(LDA_) + k0, dA + 2048);                        \
      glds16(gA + 64 * (size_t)(LDA_) + k0, dA + 4096);                        \
      glds16(gA + 96 * (size_t)(LDA_) + k0, dA + 6144);                        \
      glds16(gB + k0, dB);                                                     \
      glds16(gB + 32 * 512 + k0, dB + 2048);                                   \
      glds16(gB + 64 * 512 + k0, dB + 4096);                                   \
      glds16(gB + 96 * 512 + k0, dB + 6144);                                   \
      __syncthreads();                                                         \
      bf16x8 af00 = *(const bf16x8*)&As[aoff0 + swz0];                         \
      bf16x8 af01 = *(const bf16x8*)&As[aoff0 + swz1];                         \
      bf16x8 af10 = *(const bf16x8*)&As[aoff1 + swz0];                         \
      bf16x8 af11 = *(const bf16x8*)&As[aoff1 + swz1];                         \
      _Pragma("unroll")                                                        \
      for (int t = 0; t < 8; ++t) {                                            \
        bf16x8 bf0 = *(const bf16x8*)&Bs[t * 1024 + boffl + swz0];             \
        bf16x8 bf1 = *(const bf16x8*)&Bs[t * 1024 + boffl + swz1];             \
        acc_[0][t] = __builtin_amdgcn_mfma_f32_16x16x32_bf16(af00, bf0, acc_[0][t], 0, 0, 0); \
        acc_[0][t] = __builtin_amdgcn_mfma_f32_16x16x32_bf16(af01, bf1, acc_[0][t], 0, 0, 0); \
        acc_[1][t] = __builtin_amdgcn_mfma_f32_16x16x32_bf16(af10, bf0, acc_[1][t], 0, 0, 0); \
        acc_[1][t] = __builtin_amdgcn_mfma_f32_16x16x32_bf16(af11, bf1, acc_[1][t], 0, 0, 0); \
      }                                                                        \
      __syncthreads();                                                         \
    }                                                                          \
  }

// XCD-panel tile mapping: bid%8 ~ XCD.  The XCD owns a contiguous panel of
// (owns_m ? M : N) tiles and sweeps the full other dimension -> per-XCD
// working set ~ panel(2MB) + swept operand, L2-resident.  Bijective.
#define XCD_PANEL_MAP(mt_, nt_, owns_m_)                                       \
  int xcd = bid & 7, idx = bid >> 3;                                           \
  int per = ((owns_m_) ? (mt_) : (nt_)) >> 3;                                  \
  int pa = idx % per, pb = idx / per;                                          \
  bm = (size_t)((owns_m_) ? (xcd * per + pa) : pb) * 128;                      \
  bn = (size_t)((owns_m_) ? pb : (xcd * per + pa)) * 128;

// dots / dots2: C = alpha * A@B^T (fp32 out), coalesced LDS-staged epilogue.
__global__ __launch_bounds__(256) void gemm128_dots_kernel(
    const unsigned short* __restrict__ A, const unsigned short* __restrict__ B,
    float alpha, float* __restrict__ C, int ldc, int mt, int nt, int owns_m) {
  // 33792 B: As/Bs (32KB) overlaid with the epilogue buffer [4][16][132] fp32
  __shared__ __align__(16) char smem[33792];
  int tid = threadIdx.x, wave = tid >> 6, lane = tid & 63;
  int lrow = lane & 15, quad = lane >> 4;
  int bid = (int)blockIdx.x;
  size_t bm, bn;
  XCD_PANEL_MAP(mt, nt, owns_m)
  floatx4 zero4 = {0.f, 0.f, 0.f, 0.f};
  floatx4 acc[2][8];
#pragma unroll
  for (int i = 0; i < 2; ++i)
#pragma unroll
    for (int t = 0; t < 8; ++t) acc[i][t] = zero4;
  GEMM128_CORE(A, 512, B, bm, bn, acc, smem)
  // epilogue: per-wave 16x128 fp32 staging, then full-line float4 stores
  __syncthreads();
  float* wb = (float*)smem + wave * (16 * 132);
#pragma unroll
  for (int i = 0; i < 2; ++i) {
#pragma unroll
    for (int t = 0; t < 8; ++t)
#pragma unroll
      for (int r = 0; r < 4; ++r)
        wb[(quad * 4 + r) * 132 + t * 16 + lrow] = acc[i][t][r] * alpha;
    __syncthreads();
    size_t rowbase = bm + wave * 32 + i * 16;
#pragma unroll
    for (int p = 0; p < 8; ++p) {
      int rr = p * 2 + (lane >> 5);
      float4 v = *(const float4*)&wb[rr * 132 + ((lane & 31) << 2)];
      *(float4*)&C[(rowbase + rr) * (size_t)ldc + bn + ((lane & 31) << 2)] = v;
    }
    __syncthreads();
  }
}

// fused k/v/q2 (+ q): bid<1536: A=x [16384,512], B=Wcat slabs Wk/Wv/Wq.
// bid>=1536: q = relu(e0@Wq+bq): A=e1_hi (lda 1024), B=Wcat slab 2.
__global__ __launch_bounds__(256) void gemm128_kvq_kernel(
    const unsigned short* __restrict__ X, const unsigned short* __restrict__ E1,
    const unsigned short* __restrict__ B,
    const float* __restrict__ bk, const float* __restrict__ bv,
    const float* __restrict__ bq,
    unsigned short* __restrict__ khi, unsigned short* __restrict__ vhi,
    unsigned short* __restrict__ q2hi, unsigned short* __restrict__ qhi) {
  // 32768 B: As/Bs (32KB) overlaid with epilogue buffer [4][16][136] bf16
  __shared__ __align__(16) char smem[32768];
  int tid = threadIdx.x, wave = tid >> 6, lane = tid & 63;
  int lrow = lane & 15, quad = lane >> 4;
  int bid = (int)blockIdx.x;
  size_t bm, bn;
  const unsigned short* Aptr;
  int lda;
  unsigned short* dst;
  const float* bias;
  bool relu;
  if (bid < 1536) {
    XCD_PANEL_MAP(128, 12, 1)
    Aptr = X; lda = 512;
    int mat = (int)(bn >> 9);
    bias = mat == 0 ? bk : (mat == 1 ? bv : bq);
    dst = mat == 0 ? khi : (mat == 1 ? vhi : q2hi);
    relu = mat < 2;
  } else {
    int qb = bid - 1536;                 // 0..63
    bm = (size_t)(qb >> 2) * 128;        // 16 M-tiles of e0 (2048 rows)
    bn = 1024 + (size_t)(qb & 3) * 128;  // Wq slab of Wcat
    Aptr = E1; lda = 1024;               // e0 = e1_hi[:, :512], row stride 1024
    dst = qhi; bias = bq; relu = true;
  }
  int colbase = (int)(bn & 511);
  floatx4 zero4 = {0.f, 0.f, 0.f, 0.f};
  floatx4 acc[2][8];
#pragma unroll
  for (int i = 0; i < 2; ++i)
#pragma unroll
    for (int t = 0; t < 8; ++t) acc[i][t] = zero4;
  GEMM128_CORE(Aptr, lda, B, bm, bn, acc, smem)
  __syncthreads();
  unsigned short* wb = (unsigned short*)smem + wave * (16 * 136);
#pragma unroll
  for (int i = 0; i < 2; ++i) {
#pragma unroll
    for (int t = 0; t < 8; ++t) {
      float bvv = bias[colbase + t * 16 + lrow];
#pragma unroll
      for (int r = 0; r < 4; ++r) {
        float v = acc[i][t][r] + bvv;
        if (relu) v = fmaxf(v, 0.0f);
        wb[(quad * 4 + r) * 136 + t * 16 + lrow] = f2bf(v);
      }
    }
    __syncthreads();
    size_t rowbase = bm + wave * 32 + i * 16;
#pragma unroll
    for (int p = 0; p < 4; ++p) {
      int rr = p * 4 + (lane >> 4);
      uint4 v = *(const uint4*)&wb[rr * 136 + ((lane & 15) << 3)];
      *(uint4*)&dst[(rowbase + rr) * 512 + colbase + ((lane & 15) << 3)] = v;
    }
    __syncthreads();
  }
}

// ---------------- GEMM, 64x64 tile, reg-prefetch, optional hi/lo split -----
template <bool SPLIT, bool RELU, bool HAS_BIAS, bool WF32, bool WHI, bool WLO>
__global__ __launch_bounds__(256) void gemm64_kernel(
    const unsigned short* __restrict__ Ahi, const unsigned short* __restrict__ Alo, int lda,
    const unsigned short* __restrict__ Bhi, const unsigned short* __restrict__ Blo, int K,
    const float* __restrict__ bias, float alpha,
    float* __restrict__ Cf, int ldc,
    unsigned short* __restrict__ Chi, unsigned short* __restrict__ Clo, int ldcb) {
  __shared__ __align__(16) unsigned short AsH[64 * 32];
  __shared__ __align__(16) unsigned short BsH[64 * 32];
  __shared__ __align__(16) unsigned short AsL[64 * 32];
  __shared__ __align__(16) unsigned short BsL[64 * 32];
  int tid = threadIdx.x, wave = tid >> 6, lane = tid & 63;
  int lrow = lane & 15, quad = lane >> 4;
  size_t bm = (size_t)blockIdx.x * 64, bn = (size_t)blockIdx.y * 64;
  int row = tid >> 2, off = (tid & 3) << 3;
  size_t aoff = (bm + row) * (size_t)lda + off;
  size_t boff = (bn + row) * (size_t)K + off;

  floatx4 zero4 = {0.f, 0.f, 0.f, 0.f};
  floatx4 acc[4];
#pragma unroll
  for (int t = 0; t < 4; ++t) acc[t] = zero4;

  uint4 ah = *(const uint4*)(Ahi + aoff);
  uint4 bh = *(const uint4*)(Bhi + boff);
  uint4 al, bl;
  if (SPLIT) {
    al = *(const uint4*)(Alo + aoff);
    bl = *(const uint4*)(Blo + boff);
  }
  for (int k0 = 0; k0 < K; k0 += 32) {
    __syncthreads();
    *(uint4*)&AsH[tid * 8] = ah;
    *(uint4*)&BsH[tid * 8] = bh;
    if (SPLIT) {
      *(uint4*)&AsL[tid * 8] = al;
      *(uint4*)&BsL[tid * 8] = bl;
    }
    __syncthreads();
    if (k0 + 32 < K) {  // prefetch next chunk; overlaps the MFMAs below
      ah = *(const uint4*)(Ahi + aoff + k0 + 32);
      bh = *(const uint4*)(Bhi + boff + k0 + 32);
      if (SPLIT) {
        al = *(const uint4*)(Alo + aoff + k0 + 32);
        bl = *(const uint4*)(Blo + boff + k0 + 32);
      }
    }
    int ai = (wave * 16 + lrow) * 32 + quad * 8;
    bf16x8 aH = *(const bf16x8*)&AsH[ai];
    bf16x8 aL;
    if (SPLIT) aL = *(const bf16x8*)&AsL[ai];
#pragma unroll
    for (int t = 0; t < 4; ++t) {
      int bi = (t * 16 + lrow) * 32 + quad * 8;
      bf16x8 bH = *(const bf16x8*)&BsH[bi];
      acc[t] = __builtin_amdgcn_mfma_f32_16x16x32_bf16(aH, bH, acc[t], 0, 0, 0);
      if (SPLIT) {
        bf16x8 bL = *(const bf16x8*)&BsL[bi];
        acc[t] = __builtin_amdgcn_mfma_f32_16x16x32_bf16(aH, bL, acc[t], 0, 0, 0);
        acc[t] = __builtin_amdgcn_mfma_f32_16x16x32_bf16(aL, bH, acc[t], 0, 0, 0);
      }
    }
  }
  size_t row0 = bm + wave * 16 + quad * 4;
#pragma unroll
  for (int t = 0; t < 4; ++t) {
    int col = (int)bn + t * 16 + lrow;
    float bv = HAS_BIAS ? bias[col] : 0.0f;
#pragma unroll
    for (int r = 0; r < 4; ++r) {
      float v = acc[t][r] * alpha + bv;
      if (RELU) v = fmaxf(v, 0.0f);
      if (WF32) Cf[(row0 + r) * (size_t)ldc + col] = v;
      if (WHI) {
        unsigned short h = f2bf(v);
        Chi[(row0 + r) * (size_t)ldcb + col] = h;
        if (WLO) Clo[(row0 + r) * (size_t)ldcb + col] = f2bf(v - bf2f(h));
      }
    }
  }
}

// ---------------- top-4 register insertion ----------------
#define INSERT4(lv, li, v, col)                                   \
  do {                                                            \
    if ((v) > lv[3]) {                                            \
      float cv_ = (v); int ci_ = (col);                           \
      _Pragma("unroll")                                           \
      for (int j_ = 0; j_ < 4; ++j_) {                            \
        bool sw_ = (cv_ > lv[j_]);                                \
        float tv_ = sw_ ? lv[j_] : cv_;                           \
        int ti_ = sw_ ? li[j_] : ci_;                              \
        lv[j_] = sw_ ? cv_ : lv[j_];                              \
        li[j_] = sw_ ? ci_ : li[j_];                              \
        cv_ = tv_; ci_ = ti_;                                     \
      }                                                           \
    }                                                             \
  } while (0)

// ---------------- attention 1: 1 block (4 waves) per row of 16384 ----------
__global__ __launch_bounds__(256) void attn1_kernel(
    const float* __restrict__ dots,          // NE x NN
    const unsigned short* __restrict__ vhi,  // NN x 512 bf16
    unsigned short* __restrict__ e1_hi, unsigned short* __restrict__ e1_lo) {
  __shared__ float sm_m[4], sm_s[4];
  __shared__ unsigned long long wbest[4];
  __shared__ unsigned long long wkey_s[TOPK];

  int tid = threadIdx.x, wave = tid >> 6, lane = tid & 63;
  int rowi = blockIdx.x;
  const float4* r4 = (const float4*)(dots + (size_t)rowi * NN);

  float lv[4]; int li[4];
#pragma unroll
  for (int j = 0; j < 4; ++j) { lv[j] = -INFINITY; li[j] = 0x7fffffff; }
  unsigned long long selmask = 0ull;
  int taken = 0;

  float m_loc = -INFINITY, s_loc = 0.0f;
  for (int i = 0; i < 16; ++i) {
    float4 q = r4[tid + (i << 8)];
#pragma unroll
    for (int c = 0; c < 4; ++c) {
      float v = (&q.x)[c];
      int col = ((tid + (i << 8)) << 2) + c;
      if (v > m_loc) {
        s_loc = s_loc * __expf(m_loc - v) + 1.0f;
        m_loc = v;
      } else {
        s_loc += __expf(v - m_loc);
      }
      INSERT4(lv, li, v, col);
    }
  }
#pragma unroll
  for (int sft = 32; sft; sft >>= 1) {
    float om = __shfl_xor(m_loc, sft, 64);
    float os = __shfl_xor(s_loc, sft, 64);
    float M = fmaxf(m_loc, om);
    s_loc = s_loc * __expf(m_loc - M) + os * __expf(om - M);
    m_loc = M;
  }
  if (lane == 0) { sm_m[wave] = m_loc; sm_s[wave] = s_loc; }
  __syncthreads();
  float M = fmaxf(fmaxf(sm_m[0], sm_m[1]), fmaxf(sm_m[2], sm_m[3]));
  float Z = sm_s[0] * __expf(sm_m[0] - M) + sm_s[1] * __expf(sm_m[1] - M) +
            sm_s[2] * __expf(sm_m[2] - M) + sm_s[3] * __expf(sm_m[3] - M);

  for (int rnd = 0; rnd < TOPK; ++rnd) {
    unsigned long long key;
    if (taken < 4) {
      key = packkc(lv[0], li[0]);
    } else {  // rare: rescan this thread's 64 values from L2, excluding taken
      key = 0ull;
      for (int i = 0; i < 16; ++i) {
        float4 q = r4[tid + (i << 8)];
#pragma unroll
        for (int c = 0; c < 4; ++c) {
          int sl = i * 4 + c;
          if (!((selmask >> sl) & 1ull)) {
            int col = ((tid + (i << 8)) << 2) + c;
            unsigned long long kk = packkc((&q.x)[c], col);
            if (kk > key) key = kk;
          }
        }
      }
    }
#pragma unroll
    for (int sft = 32; sft; sft >>= 1) {
      unsigned long long ok = shfl_xor_u64(key, sft);
      if (ok > key) key = ok;
    }
    if (lane == 0) wbest[wave] = key;
    __syncthreads();
    unsigned long long w = wbest[0];
    if (wbest[1] > w) w = wbest[1];
    if (wbest[2] > w) w = wbest[2];
    if (wbest[3] > w) w = wbest[3];
    if (tid == 0) wkey_s[rnd] = w;
    int wcol = unpack_col(w);
    if (((wcol >> 2) & 255) == tid) {
      int sl = ((wcol >> 10) << 2) | (wcol & 3);
      selmask |= (1ull << sl);
      if (taken < 4) {
#pragma unroll
        for (int j = 0; j < 3; ++j) { lv[j] = lv[j + 1]; li[j] = li[j + 1]; }
      }
      ++taken;
    }
    __syncthreads();
  }

  const float inv_den = 1.0f / (1.0f + (float)NN * EPS_F);
  float invZ = 1.0f / Z;
  float u0 = 0.f, u1 = 0.f;
#pragma unroll
  for (int j = 0; j < TOPK; ++j) {
    unsigned long long w = wkey_s[j];
    int col = unpack_col(w);
    float val = unpack_val(w);
    float a = (__expf(val - M) * invZ + EPS_F) * inv_den;
    const unsigned short* vr = vhi + (size_t)col * 512;
    u0 += a * bf2f(vr[tid]);
    u1 += a * bf2f(vr[tid + 256]);
  }
  size_t o = (size_t)rowi * 1024 + 512;
  unsigned short h0 = f2bf(u0), h1 = f2bf(u1);
  e1_hi[o + tid] = h0;             e1_lo[o + tid] = f2bf(u0 - bf2f(h0));
  e1_hi[o + tid + 256] = h1;       e1_lo[o + tid + 256] = f2bf(u1 - bf2f(h1));
}

// ---------------- attention 2: 1 wave per row of 2048 (4 rows/block) -------
__global__ __launch_bounds__(256) void attn2_kernel(const float* __restrict__ dots2,
                                                    float* __restrict__ Hout) {
  int tid = threadIdx.x, wave = tid >> 6, lane = tid & 63;
  int rowi = blockIdx.x * 4 + wave;
  const float4* r4 = (const float4*)(dots2 + (size_t)rowi * NE);

  float d[32];
  float m = -INFINITY;
#pragma unroll
  for (int i = 0; i < 8; ++i) {
    float4 q = r4[lane + (i << 6)];
#pragma unroll
    for (int c = 0; c < 4; ++c) {
      d[i * 4 + c] = (&q.x)[c];
      m = fmaxf(m, d[i * 4 + c]);
    }
  }
#pragma unroll
  for (int sft = 32; sft; sft >>= 1) m = fmaxf(m, __shfl_xor(m, sft, 64));

  float s = 0.f;
#pragma unroll
  for (int j = 0; j < 32; ++j) { d[j] = __expf(d[j] - m); s += d[j]; }
#pragma unroll
  for (int sft = 32; sft; sft >>= 1) s += __shfl_xor(s, sft, 64);
  float invZ = 1.0f / s;

  float lv[4]; int li[4];
#pragma unroll
  for (int j = 0; j < 4; ++j) { lv[j] = -INFINITY; li[j] = 0x7fffffff; }
#pragma unroll
  for (int i = 0; i < 8; ++i) {
#pragma unroll
    for (int c = 0; c < 4; ++c) {
      int col = ((lane + (i << 6)) << 2) + c;
      INSERT4(lv, li, d[i * 4 + c], col);
    }
  }

  unsigned selmask = 0;
  int taken = 0;
  for (int rnd = 0; rnd < TOPK; ++rnd) {
    unsigned long long key;
    if (taken < 4) {
      key = packkc(lv[0], li[0]);
    } else {
      key = 0ull;
#pragma unroll
      for (int j = 0; j < 32; ++j) {
        if (!((selmask >> j) & 1u)) {
          int col = ((lane + ((j >> 2) << 6)) << 2) + (j & 3);
          unsigned long long kk = packkc(d[j], col);
          if (kk > key) key = kk;
        }
      }
    }
#pragma unroll
    for (int sft = 32; sft; sft >>= 1) {
      unsigned long long ok = shfl_xor_u64(key, sft);
      if (ok > key) key = ok;
    }
    int wcol = unpack_col(key);
    if (((wcol >> 2) & 63) == lane) {
      int sl = ((wcol >> 8) << 2) | (wcol & 3);
      selmask |= (1u << sl);
      if (taken < 4) {
#pragma unroll
        for (int j = 0; j < 3; ++j) { lv[j] = lv[j + 1]; li[j] = li[j + 1]; }
      }
      ++taken;
    }
  }

  float* hr = Hout + (size_t)rowi * NE;
#pragma unroll
  for (int i = 0; i < 8; ++i) {
    float4 o;
#pragma unroll
    for (int c = 0; c < 4; ++c) {
      int sl = i * 4 + c;
      (&o.x)[c] = ((selmask >> sl) & 1u) ? d[sl] * invZ : 0.0f;
    }
    ((float4*)hr)[lane + (i << 6)] = o;
  }
}

// ---------------------------------------------------------------------------
extern "C" void kernel_launch(void* const* d_in, const int* in_sizes, int n_in,
                              void* d_out, int out_size, void* d_ws, size_t ws_size,
                              hipStream_t stream) {
  (void)in_sizes; (void)n_in; (void)out_size; (void)ws_size;
  const float* inputs  = (const float*)d_in[0];
  const float* noise   = (const float*)d_in[1];
  const float* edges_mu = (const float*)d_in[2];
  const float* edges_ls = (const float*)d_in[3];
  const float* Wq = (const float*)d_in[4];
  const float* bq = (const float*)d_in[5];
  const float* Wk = (const float*)d_in[6];
  const float* bk = (const float*)d_in[7];
  const float* Wv = (const float*)d_in[8];
  const float* bv = (const float*)d_in[9];
  const float* W1 = (const float*)d_in[10];
  const float* b1 = (const float*)d_in[11];
  const float* W2 = (const float*)d_in[12];
  const float* b2 = (const float*)d_in[13];
  const float* ln_in_w = (const float*)d_in[14];
  const float* ln_in_b = (const float*)d_in[15];
  const float* ln_e_w = (const float*)d_in[16];
  const float* ln_e_b = (const float*)d_in[17];

  float* out_e  = (float*)d_out;                  // [2048,512]
  float* out_H  = out_e + (size_t)NE * 512;       // [16384,2048]
  float* out_d2 = out_H + (size_t)NN * NE;        // [16384,2048]

  const size_t MB = 1024 * 1024;
  // Scratch in the H output region (dead before attn2 writes H).
  unsigned char* hb = (unsigned char*)out_H;
  unsigned short* x_hi  = (unsigned short*)(hb);                 // 16 MB
  unsigned short* k_hi  = (unsigned short*)(hb + 16 * MB);       // 16 MB
  unsigned short* v_hi  = (unsigned short*)(hb + 32 * MB);       // 16 MB
  unsigned short* q2_hi = (unsigned short*)(hb + 48 * MB);       // 16 MB
  unsigned short* WcatT = (unsigned short*)(hb + 64 * MB);       // 1.5 MB [Wk;Wv;Wq]^T
  unsigned short* W1Th  = (unsigned short*)(hb + 66 * MB);       // 1 MB
  unsigned short* W1Tl  = (unsigned short*)(hb + 67 * MB);       // 1 MB
  unsigned short* W2Th  = (unsigned short*)(hb + 68 * MB);       // 0.5 MB
  unsigned short* W2Tl  = (unsigned short*)(hb + 68 * MB + 512 * 1024);
  unsigned short* e1_hi = (unsigned short*)(hb + 70 * MB);       // 4 MB [2048,1024]
  unsigned short* e1_lo = (unsigned short*)(hb + 74 * MB);       // 4 MB
  unsigned short* q_hi  = (unsigned short*)(hb + 78 * MB);       // 2 MB
  unsigned short* h_hi  = (unsigned short*)(hb + 80 * MB);       // 2 MB
  unsigned short* h_lo  = (unsigned short*)(hb + 82 * MB);       // 2 MB
  unsigned short* e_hi  = (unsigned short*)(hb + 84 * MB);       // 2 MB
  unsigned short* WkT   = WcatT;                                 // slab 0
  // dots fp32 scratch lives in the dots2 output region (consumed by attn1
  // before the dots2 GEMM overwrites the region).
  float* dots = out_d2;
  unsigned short* k2_hi = (unsigned short*)d_ws;                 // 2 MB true ws

  dim3 tb(256);
  dim3 t32(32, 8);

  // all weight transposes in one launch
  transpose_all_kernel<<<dim3(16, 32, 5), t32, 0, stream>>>(
      Wk, Wv, Wq, WcatT, W1, W1Th, W1Tl, W2, W2Th, W2Tl);
  // both layernorms in one launch
  ln_all_kernel<<<NN + NE, tb, 0, stream>>>(
      inputs, ln_in_w, ln_in_b, x_hi,
      noise, edges_mu, edges_ls, ln_e_w, ln_e_b, e1_hi, e1_lo);

  // k = relu(x@Wk+bk), v = relu(x@Wv+bv), q2 = x@Wq+bq, q = relu(e0@Wq+bq)
  // (one fused launch; q-blocks appended — independent of kvq blocks)
  gemm128_kvq_kernel<<<dim3(1600), tb, 0, stream>>>(
      x_hi, e1_hi, WcatT, bk, bv, bq, k_hi, v_hi, q2_hi, q_hi);
  // dots = q@k^T * SCALE -> dots2-region scratch
  // XCD panel on N (k rows): each XCD owns 16 N-tiles (2MB of k), sweeps q.
  gemm128_dots_kernel<<<dim3(2048), tb, 0, stream>>>(
      q_hi, k_hi, SCALE_F, dots, NN, 16, 128, 0);
  // attn1 -> updates into e1[:,512:]
  attn1_kernel<<<NE, tb, 0, stream>>>(dots, v_hi, e1_hi, e1_lo);
  // h = relu(e1@W1+b1)  (SPLIT)
  gemm64_kernel<true, true, true, false, true, true><<<dim3(32, 8), tb, 0, stream>>>(
      e1_hi, e1_lo, 1024, W1Th, W1Tl, 1024, b1, 1.f, nullptr, 0, h_hi, h_lo, 512);
  // e = h@W2+b2  (SPLIT) -> OUTPUT 0 + bf16 hi
  gemm64_kernel<true, false, true, true, true, false><<<dim3(32, 8), tb, 0, stream>>>(
      h_hi, h_lo, 512, W2Th, W2Tl, 512, b2, 1.f, out_e, 512, e_hi, nullptr, 512);
  // k2 = relu(e@Wk+bk)
  gemm64_kernel<false, true, true, false, true, false><<<dim3(32, 8), tb, 0, stream>>>(
      e_hi, nullptr, 512, WkT, nullptr, 512, bk, 1.f, nullptr, 0, k2_hi, nullptr, 512);
  // dots2 = q2@k2^T * SCALE -> OUTPUT 2 (overwrites dots scratch, consumed)
  // XCD panel on M (q2 rows): each XCD owns 16 M-tiles (2MB of q2), sweeps k2.
  gemm128_dots_kernel<<<dim3(2048), tb, 0, stream>>>(
      q2_hi, k2_hi, SCALE_F, out_d2, NE, 128, 16, 1);
  // attn2 -> OUTPUT 1 (H), overwrites all H-region scratch (dead)
  attn2_kernel<<<NN / 4, tb, 0, stream>>>(out_d2, out_H);
}